// Round 8
// baseline (520.673 us; speedup 1.0000x reference)
//
#include <hip/hip_runtime.h>
#include <hip/hip_bf16.h>
#include <math.h>

using bf16_t = __bf16;
using bf16x8 = __attribute__((ext_vector_type(8))) __bf16;
using f32x4  = __attribute__((ext_vector_type(4))) float;

typedef __attribute__((address_space(1))) const void* gas_ptr;
typedef __attribute__((address_space(3))) void*       las_ptr;

// ---------------------------------------------------------------------------
// Problem constants
// ---------------------------------------------------------------------------
#define BATCH    2
#define SEQ      2048
#define DMODEL   2048
#define DINNER   4096
#define DSTATE   16
#define NROWS    (BATCH * SEQ)          // 4096

// ---------------------------------------------------------------------------
// merged fp32 -> bf16 cast: W_in (16.8M), x (8.4M), W_out (8.4M), 8 elem/thread
// ---------------------------------------------------------------------------
#define CAST_C0  (2 * DINNER * DMODEL / 8)   // W_in chunks  = 2097152
#define CAST_C1  (NROWS * DMODEL / 8)        // x chunks     = 1048576
#define CAST_C2  (DMODEL * DINNER / 8)       // W_out chunks = 1048576
#define CAST_BLOCKS ((CAST_C0 + CAST_C1 + CAST_C2) / 256)

__global__ __launch_bounds__(256)
void cast_all_kernel(const float* __restrict__ s0, bf16_t* __restrict__ d0,
                     const float* __restrict__ s1, bf16_t* __restrict__ d1,
                     const float* __restrict__ s2, bf16_t* __restrict__ d2)
{
    int i = blockIdx.x * 256 + threadIdx.x;
    const float* src; bf16_t* dst; int j;
    if (i < CAST_C0)                  { src = s0; dst = d0; j = i; }
    else if (i < CAST_C0 + CAST_C1)   { src = s1; dst = d1; j = i - CAST_C0; }
    else                              { src = s2; dst = d2; j = i - CAST_C0 - CAST_C1; }
    size_t off = (size_t)j * 8;
    float4 a = *(const float4*)(src + off);
    float4 b = *(const float4*)(src + off + 4);
    bf16x8 o;
    o[0] = (bf16_t)a.x; o[1] = (bf16_t)a.y; o[2] = (bf16_t)a.z; o[3] = (bf16_t)a.w;
    o[4] = (bf16_t)b.x; o[5] = (bf16_t)b.y; o[6] = (bf16_t)b.z; o[7] = (bf16_t)b.w;
    *(bf16x8*)(dst + off) = o;
}

// ---------------------------------------------------------------------------
// Schedule primitives. Ledger: R2/R3 counted-vmcnt null-to-negative;
// runtime LDS offsets wreck codegen; R4 8-MFMA phases pay 2x barrier cost;
// R7 (clean A/B): 1-block/CU phase-split GEMM2 loses to 2-block/CU plain
// 128^2 (cross-block overlap hides barrier drains) -> GEMM2 stays gemm_bt2.
// ---------------------------------------------------------------------------
#define GBAR()     asm volatile("s_barrier" ::: "memory")
#define WLGKM0()   asm volatile("s_waitcnt lgkmcnt(0)" ::: "memory")
#define WVM0()     asm volatile("s_waitcnt vmcnt(0)" ::: "memory")

#define MM(m, n, av, bv) \
    acc[m][n] = __builtin_amdgcn_mfma_f32_16x16x32_bf16(av, bv, acc[m][n], 0, 0, 0)

// ---------------------------------------------------------------------------
// GEMM1 (256x256 tile, BK=64, 8 waves = 2M x 4N, 4-phase schedule):
//   C = A(4096x2048) * B(8192x2048)^T ; col<4096 -> xi fp32, else sigmoid->g
// R8: launched as TWO half-grids (ybase 0/8) -- same work, ~82 us each;
// drops the rocprof top-5 threshold so hidden kernels surface w/ counters.
// ---------------------------------------------------------------------------
#define MFMA_COL2(nA, nB, bA, bB)                                   \
    MM(0, nA, a0, bA); MM(0, nB, a0, bB); MM(1, nA, a1, bA); MM(1, nB, a1, bB); \
    MM(2, nA, a2, bA); MM(2, nB, a2, bB); MM(3, nA, a3, bA); MM(3, nB, a3, bB); \
    MM(4, nA, a4, bA); MM(4, nB, a4, bB); MM(5, nA, a5, bA); MM(5, nB, a5, bB); \
    MM(6, nA, a6, bA); MM(6, nB, a6, bB); MM(7, nA, a7, bA); MM(7, nB, a7, bB)

__global__ __launch_bounds__(512, 2)
void gemm1_256(const bf16_t* __restrict__ A, const bf16_t* __restrict__ B,
               float* __restrict__ outf, bf16_t* __restrict__ outg, int ybase)
{
    constexpr int K  = DMODEL;   // 2048
    constexpr int NT = K / 64;   // 32 K-tiles

    __shared__ bf16_t As[2][256 * 64];   // 32 KiB per buffer
    __shared__ bf16_t Bs[2][256 * 64];   // total LDS = 128 KiB -> 1 block/CU

    const int t    = threadIdx.x;
    const int w    = t >> 6;          // wave 0..7
    const int lane = t & 63;
    const int wm   = w >> 2;          // 0..1  (M half: 128 rows)
    const int wn   = w & 3;           // 0..3  (N quarter: 64 cols)
    const int lo   = lane & 15;
    const int q    = lane >> 4;
    const int swz  = lo & 7;

    const int m0 = (blockIdx.y + ybase) * 256;
    const int n0 = blockIdx.x * 256;

    // staging lane geometry (proven scheme, SQ_LDS_BANK_CONFLICT == 0):
    const int r_l   = lane >> 3;
    const int cb    = (lane & 7) ^ r_l;
    const int laneg = r_l * K + cb * 8;          // lane offset in elements

    const bf16_t* Abase = A + (size_t)(m0 + w * 32) * K;
    const bf16_t* Bbase = B + (size_t)(n0 + w * 32) * K;

#define STAGE_A(BUF, kk) do {                                                  \
    _Pragma("unroll")                                                          \
    for (int c = 0; c < 4; ++c)                                                \
        __builtin_amdgcn_global_load_lds(                                      \
            (gas_ptr)(Abase + (kk) + c * 8 * K + laneg),                       \
            (las_ptr)&As[BUF][(w * 32 + c * 8) * 64], 16, 0, 0);               \
} while (0)
#define STAGE_B(BUF, kk) do {                                                  \
    _Pragma("unroll")                                                          \
    for (int c = 0; c < 4; ++c)                                                \
        __builtin_amdgcn_global_load_lds(                                      \
            (gas_ptr)(Bbase + (kk) + c * 8 * K + laneg),                       \
            (las_ptr)&Bs[BUF][(w * 32 + c * 8) * 64], 16, 0, 0);               \
} while (0)

    // fragment reads: row-swizzled col-block ((s*4+q) ^ (row&7))
#define LDA_F(BUF, m, s) \
    (*(const bf16x8*)&As[BUF][(wm * 128 + (m) * 16 + lo) * 64 + ((((s) * 4 + q) ^ swz) * 8)])
#define LDB_F(BUF, n, s) \
    (*(const bf16x8*)&Bs[BUF][(wn * 64  + (n) * 16 + lo) * 64 + ((((s) * 4 + q) ^ swz) * 8)])

    f32x4 acc[8][4];
#pragma unroll
    for (int i = 0; i < 8; ++i)
#pragma unroll
        for (int j = 0; j < 4; ++j) acc[i][j] = (f32x4){0.f, 0.f, 0.f, 0.f};

    // prologue: stage K-tile 0 into buffer 0, drain, barrier
    STAGE_A(0, 0);
    STAGE_B(0, 0);
    WVM0();
    GBAR();

#define TILE_STEP(CUR, NXT, tkv) do {                                          \
    const int  k1_  = ((tkv) + 1) * 64;                                        \
    const bool pre_ = ((tkv) + 1) < NT;                                        \
    bf16x8 a0, a1, a2, a3, a4, a5, a6, a7, b0, b1, b2, b3;                     \
    /* ---- sub0: A frags s0 + B n0..1 s0 ; stage A(t+1) ---- */               \
    a0 = LDA_F(CUR, 0, 0); a1 = LDA_F(CUR, 1, 0);                              \
    a2 = LDA_F(CUR, 2, 0); a3 = LDA_F(CUR, 3, 0);                              \
    a4 = LDA_F(CUR, 4, 0); a5 = LDA_F(CUR, 5, 0);                              \
    a6 = LDA_F(CUR, 6, 0); a7 = LDA_F(CUR, 7, 0);                              \
    b0 = LDB_F(CUR, 0, 0); b1 = LDB_F(CUR, 1, 0);                              \
    if (pre_) STAGE_A(NXT, k1_);                                               \
    GBAR(); WLGKM0();                                                          \
    __builtin_amdgcn_s_setprio(1);                                             \
    MFMA_COL2(0, 1, b0, b1);                                                   \
    __builtin_amdgcn_s_setprio(0);                                             \
    GBAR();                                                                    \
    /* ---- sub1: B n2..3 s0 ; stage B(t+1) ---- */                            \
    b2 = LDB_F(CUR, 2, 0); b3 = LDB_F(CUR, 3, 0);                              \
    if (pre_) STAGE_B(NXT, k1_);                                               \
    GBAR(); WLGKM0();                                                          \
    __builtin_amdgcn_s_setprio(1);                                             \
    MFMA_COL2(2, 3, b2, b3);                                                   \
    __builtin_amdgcn_s_setprio(0);                                             \
    GBAR();                                                                    \
    /* ---- sub2: A frags s1 + B n0..1 s1 ---- */                              \
    a0 = LDA_F(CUR, 0, 1); a1 = LDA_F(CUR, 1, 1);                              \
    a2 = LDA_F(CUR, 2, 1); a3 = LDA_F(CUR, 3, 1);                              \
    a4 = LDA_F(CUR, 4, 1); a5 = LDA_F(CUR, 5, 1);                              \
    a6 = LDA_F(CUR, 6, 1); a7 = LDA_F(CUR, 7, 1);                              \
    b0 = LDB_F(CUR, 0, 1); b1 = LDB_F(CUR, 1, 1);                              \
    GBAR(); WLGKM0();                                                          \
    __builtin_amdgcn_s_setprio(1);                                             \
    MFMA_COL2(0, 1, b0, b1);                                                   \
    __builtin_amdgcn_s_setprio(0);                                             \
    GBAR();                                                                    \
    /* ---- sub3: B n2..3 s1 ; drain stages (3 phases of flight) ---- */       \
    b2 = LDB_F(CUR, 2, 1); b3 = LDB_F(CUR, 3, 1);                              \
    GBAR(); WLGKM0();                                                          \
    __builtin_amdgcn_s_setprio(1);                                             \
    MFMA_COL2(2, 3, b2, b3);                                                   \
    __builtin_amdgcn_s_setprio(0);                                             \
    WVM0();                                                                    \
    GBAR();                                                                    \
} while (0)

#pragma unroll 1
    for (int tk = 0; tk < NT; tk += 2) {
        TILE_STEP(0, 1, tk);
        TILE_STEP(1, 0, tk + 1);
    }

    // epilogue: C/D layout col = lane&15, row = quad*4 + reg  [m89/m91]
#pragma unroll
    for (int m = 0; m < 8; ++m) {
        const int rbase = m0 + wm * 128 + m * 16 + q * 4;
#pragma unroll
        for (int n = 0; n < 4; ++n) {
            const int col = n0 + wn * 64 + n * 16 + lo;
#pragma unroll
            for (int rr = 0; rr < 4; ++rr) {
                float v   = acc[m][n][rr];
                int   row = rbase + rr;
                if (col < DINNER) {
                    outf[(size_t)row * DINNER + col] = v;              // xi fp32
                } else {
                    float sg = 1.f / (1.f + __expf(-v));               // sigmoid(gate)
                    outg[(size_t)row * DINNER + (col - DINNER)] = (bf16_t)sg;
                }
            }
        }
    }
}

// ---------------------------------------------------------------------------
// bf16 GEMM  C = A(MxK) * B(NxK)^T, 128x128 tile, BK=64, global_load_lds
// width=16 + XOR swizzle. GEMM2 (known-best config; 64 KiB LDS -> 2 blocks/CU
// gives cross-block overlap that hides barrier drains -- R7 A/B).
//   out = acc * (4096 * rowscale[row])
// ---------------------------------------------------------------------------
__global__ __launch_bounds__(256)
void gemm_bt2(const bf16_t* __restrict__ A, const bf16_t* __restrict__ B, int K,
              float* __restrict__ outf, const float* __restrict__ rowscale)
{
    constexpr int LDK = 64;            // unpadded: required by global_load_lds
    __shared__ bf16_t As[128 * LDK];
    __shared__ bf16_t Bs[128 * LDK];

    const int t    = threadIdx.x;
    const int m0   = blockIdx.y * 128;
    const int n0   = blockIdx.x * 128;
    const int w    = t >> 6;
    const int lane = t & 63;
    const int wr   = (w >> 1) * 64;
    const int wc   = (w & 1) * 64;
    const int lo   = lane & 15;
    const int q    = lane >> 4;

    const int r_l  = lane >> 3;
    const int cb   = (lane & 7) ^ r_l;
    const int laneA = (w * 32 + r_l) * K + cb * 8;
    const bf16_t* Abase = A + (size_t)m0 * K;
    const bf16_t* Bbase = B + (size_t)n0 * K;

    f32x4 acc[4][4];
#pragma unroll
    for (int i = 0; i < 4; ++i)
#pragma unroll
        for (int j = 0; j < 4; ++j) acc[i][j] = (f32x4){0.f, 0.f, 0.f, 0.f};

    for (int k0 = 0; k0 < K; k0 += 64) {
#pragma unroll
        for (int c = 0; c < 4; ++c) {
            const int uoff   = k0 + c * 8 * K;            // uniform (SGPR)
            const int lo_off = (w * 32 + c * 8) * LDK;    // wave-uniform LDS
            __builtin_amdgcn_global_load_lds((gas_ptr)(Abase + uoff + laneA),
                                             (las_ptr)&As[lo_off], 16, 0, 0);
            __builtin_amdgcn_global_load_lds((gas_ptr)(Bbase + uoff + laneA),
                                             (las_ptr)&Bs[lo_off], 16, 0, 0);
        }
        __syncthreads();

        const int swz = lo & 7;
#pragma unroll
        for (int ks = 0; ks < 2; ++ks) {
            const int kk = ((ks * 4 + q) ^ swz) * 8;
            bf16x8 af[4], bfv[4];
#pragma unroll
            for (int mi = 0; mi < 4; ++mi)
                af[mi] = *(const bf16x8*)&As[(wr + mi * 16 + lo) * LDK + kk];
#pragma unroll
            for (int ni = 0; ni < 4; ++ni)
                bfv[ni] = *(const bf16x8*)&Bs[(wc + ni * 16 + lo) * LDK + kk];
#pragma unroll
            for (int mi = 0; mi < 4; ++mi)
#pragma unroll
                for (int ni = 0; ni < 4; ++ni)
                    acc[mi][ni] = __builtin_amdgcn_mfma_f32_16x16x32_bf16(
                        af[mi], bfv[ni], acc[mi][ni], 0, 0, 0);
        }
        __syncthreads();
    }

#pragma unroll
    for (int mi = 0; mi < 4; ++mi) {
#pragma unroll
        for (int ni = 0; ni < 4; ++ni) {
            const int col   = n0 + wc + ni * 16 + lo;
            const int rbase = m0 + wr + mi * 16 + q * 4;
#pragma unroll
            for (int rr = 0; rr < 4; ++rr) {
                int row = rbase + rr;
                outf[(size_t)row * DMODEL + col] =
                    acc[mi][ni][rr] * (4096.0f * rowscale[row]);
            }
        }
    }
}

// ---------------------------------------------------------------------------
// fused depthwise causal conv(4) + SiLU + dt-matvec + u extraction.
// ---------------------------------------------------------------------------
#define RROWS 4
__global__ __launch_bounds__(256)
void conv_dt_kernel(const float* __restrict__ xi, const float* __restrict__ cw,
                    const float* __restrict__ cbias, const float* __restrict__ wdt,
                    const float* __restrict__ bdt, float* __restrict__ uT,
                    float* __restrict__ dtT)
{
    const int r0 = blockIdx.x * RROWS;          // 4 rows, same batch (SEQ%4==0)
    const int t  = threadIdx.x;
    const int s0 = r0 & (SEQ - 1);
    const int b  = r0 >> 11;

    float xsv[RROWS][16];                        // silu(conv) for 4 rows x 16 ch
#pragma unroll
    for (int j = 0; j < 4; ++j) {
        const int c = t * 4 + j * 1024;
        float4 w0 = *(const float4*)(cw + (c + 0) * 4);
        float4 w1 = *(const float4*)(cw + (c + 1) * 4);
        float4 w2 = *(const float4*)(cw + (c + 2) * 4);
        float4 w3 = *(const float4*)(cw + (c + 3) * 4);
        float4 cbv = *(const float4*)(cbias + c);
        float4 xr[RROWS + 3];
#pragma unroll
        for (int i = 0; i < RROWS + 3; ++i) {
            int ss = s0 - 3 + i;
            if (ss >= 0)
                xr[i] = *(const float4*)(xi + (size_t)(r0 - 3 + i) * DINNER + c);
            else
                xr[i] = make_float4(0.f, 0.f, 0.f, 0.f);
        }
#pragma unroll
        for (int rr = 0; rr < RROWS; ++rr) {
            float4 a = xr[rr], bv = xr[rr + 1], cc = xr[rr + 2], d = xr[rr + 3];
            float v0 = cbv.x + w0.x * a.x + w0.y * bv.x + w0.z * cc.x + w0.w * d.x;
            float v1 = cbv.y + w1.x * a.y + w1.y * bv.y + w1.z * cc.y + w1.w * d.y;
            float v2 = cbv.z + w2.x * a.z + w2.y * bv.z + w2.z * cc.z + w2.w * d.z;
            float v3 = cbv.w + w3.x * a.w + w3.y * bv.w + w3.z * cc.w + w3.w * d.w;
            xsv[rr][j * 4 + 0] = v0 / (1.f + __expf(-v0));
            xsv[rr][j * 4 + 1] = v1 / (1.f + __expf(-v1));
            xsv[rr][j * 4 + 2] = v2 / (1.f + __expf(-v2));
            xsv[rr][j * 4 + 3] = v3 / (1.f + __expf(-v3));
        }
    }

    if (t < 4) {
#pragma unroll
        for (int rr = 0; rr < RROWS; ++rr)
#pragma unroll
            for (int k = 0; k < 4; ++k)
                uT[b * (DSTATE * SEQ) + (t * 4 + k) * SEQ + (s0 + rr)] = xsv[rr][k];
    }

    float acc[DSTATE][RROWS];
#pragma unroll
    for (int e = 0; e < DSTATE; ++e)
#pragma unroll
        for (int rr = 0; rr < RROWS; ++rr) acc[e][rr] = 0.f;

#pragma unroll
    for (int e = 0; e < DSTATE; ++e) {
        const float* wrow = wdt + (size_t)e * DINNER;
#pragma unroll
        for (int j = 0; j < 4; ++j) {
            float4 wv = *(const float4*)(wrow + t * 4 + j * 1024);
#pragma unroll
            for (int rr = 0; rr < RROWS; ++rr)
                acc[e][rr] += wv.x * xsv[rr][j * 4 + 0] + wv.y * xsv[rr][j * 4 + 1]
                            + wv.z * xsv[rr][j * 4 + 2] + wv.w * xsv[rr][j * 4 + 3];
        }
    }

#pragma unroll
    for (int e = 0; e < DSTATE; ++e)
#pragma unroll
        for (int rr = 0; rr < RROWS; ++rr) {
            float v = acc[e][rr];
#pragma unroll
            for (int off = 32; off > 0; off >>= 1) v += __shfl_down(v, off);
            acc[e][rr] = v;
        }
    __shared__ float red[4][DSTATE][RROWS];
    const int w = t >> 6;
    if ((t & 63) == 0) {
#pragma unroll
        for (int e = 0; e < DSTATE; ++e)
#pragma unroll
            for (int rr = 0; rr < RROWS; ++rr) red[w][e][rr] = acc[e][rr];
    }
    __syncthreads();
    if (t < 64) {
        int e = t >> 2, rr = t & 3;
        float tot = red[0][e][rr] + red[1][e][rr] + red[2][e][rr] + red[3][e][rr] + bdt[e];
        float dtv = (tot > 20.f) ? tot : log1pf(__expf(tot));
        dtT[b * (DSTATE * SEQ) + e * SEQ + (s0 + rr)] = dtv;
    }
}

// ---------------------------------------------------------------------------
// segmented parallel scan: 2 blocks (one per batch) x 512 threads
//   = 16 states x 32 segments of 64 steps.  Sequential depth 160 vs 2048.
//   (R6: -54 us vs the 64-thread serial version.)
// ---------------------------------------------------------------------------
__global__ __launch_bounds__(512)
void scan2_kernel(const float* __restrict__ dtT, const float* __restrict__ uT,
                  const float* __restrict__ A_log, float* __restrict__ result)
{
    __shared__ float cont[SEQ * 17];            // 139264 B
    __shared__ float segP[DSTATE][32];
    __shared__ float segH[DSTATE][32];
    __shared__ float hin[DSTATE][32];

    const int b   = blockIdx.x;
    const int t   = threadIdx.x;
    const int n   = t >> 5;                     // 0..15
    const int seg = t & 31;                     // 0..31
    const float An = -expf(A_log[n]);

    const float* dtp = dtT + b * (DSTATE * SEQ) + n * SEQ + seg * 64;
    const float* up  = uT  + b * (DSTATE * SEQ) + n * SEQ + seg * 64;

    // pass 1: (P, H) for this segment assuming h_in = 0
    float P = 1.f, H = 0.f;
    for (int i = 0; i < 64; i += 4) {
        float4 dv = *(const float4*)(dtp + i);
        float4 uv = *(const float4*)(up + i);
        float a;
        a = 1.f + dv.x; P *= a; H = H * a + uv.x;
        a = 1.f + dv.y; P *= a; H = H * a + uv.y;
        a = 1.f + dv.z; P *= a; H = H * a + uv.z;
        a = 1.f + dv.w; P *= a; H = H * a + uv.w;
    }
    segP[n][seg] = P;
    segH[n][seg] = H;
    __syncthreads();

    // exclusive affine prefix over 32 segments, serial per state
    if (t < DSTATE) {
        float h = 0.f;
#pragma unroll
        for (int j = 0; j < 32; ++j) {
            hin[t][j] = h;
            h = segP[t][j] * h + segH[t][j];
        }
    }
    __syncthreads();

    // pass 2: replay with correct h_in; write h*An (n-swizzled)
    {
        float h = hin[n][seg];
        const int nsw = (n + seg) & 15;
        for (int i = 0; i < 64; i += 4) {
            float4 dv = *(const float4*)(dtp + i);
            float4 uv = *(const float4*)(up + i);
            const int s = seg * 64 + i;
            h = h * (1.f + dv.x) + uv.x; cont[(s + 0) * 17 + nsw] = h * An;
            h = h * (1.f + dv.y) + uv.y; cont[(s + 1) * 17 + nsw] = h * An;
            h = h * (1.f + dv.z) + uv.z; cont[(s + 2) * 17 + nsw] = h * An;
            h = h * (1.f + dv.w) + uv.w; cont[(s + 3) * 17 + nsw] = h * An;
        }
    }
    __syncthreads();

    // reduce over the 16 states; lane stride 17 words -> conflict-free
#pragma unroll
    for (int k = 0; k < 4; ++k) {
        const int s = t + k * 512;
        float sum = 0.f;
#pragma unroll
        for (int j = 0; j < DSTATE; ++j) sum += cont[s * 17 + j];
        result[b * SEQ + s] = sum;
    }
}

// ---------------------------------------------------------------------------
// launch
// ---------------------------------------------------------------------------
extern "C" void kernel_launch(void* const* d_in, const int* in_sizes, int n_in,
                              void* d_out, int out_size, void* d_ws, size_t ws_size,
                              hipStream_t stream)
{
    const float* x      = (const float*)d_in[0];
    const float* W_in   = (const float*)d_in[1];
    const float* conv_w = (const float*)d_in[2];
    const float* conv_b = (const float*)d_in[3];
    const float* W_dt   = (const float*)d_in[4];
    const float* b_dt   = (const float*)d_in[5];
    const float* A_log  = (const float*)d_in[6];
    const float* W_out  = (const float*)d_in[7];
    float* out = (float*)d_out;

    const size_t MB = 1u << 20;
    char* w = (char*)d_ws;
    bf16_t* xb   = (bf16_t*)(w);                     // 16 MB
    bf16_t* wib  = (bf16_t*)(w + 16 * MB);           // 32 MB
    bf16_t* wob  = (bf16_t*)(w + 48 * MB);           // 16 MB
    float*  xi   = (float*) (w + 64 * MB);           // 64 MB
    bf16_t* g    = (bf16_t*)(w + 128 * MB);          // 32 MB
    float*  uT   = (float*) (w + 160 * MB);                      // 256 KB
    float*  dtT  = (float*) (w + 160 * MB + 262144);             // 256 KB
    float*  res  = (float*) (w + 160 * MB + 2 * 262144);         // 16 KB

    // 1. merged casts to bf16
    cast_all_kernel<<<CAST_BLOCKS, 256, 0, stream>>>(W_in, wib, x, xb, W_out, wob);

    // 2. GEMM1 split into two half-grids (diagnostic: lowers top-5 threshold
    //    to ~84 us so hidden kernels surface with counters)
    gemm1_256<<<dim3(32, 8), 512, 0, stream>>>(xb, wib, xi, g, 0);
    gemm1_256<<<dim3(32, 8), 512, 0, stream>>>(xb, wib, xi, g, 8);

    // 3. fused conv + silu + dt + u  (xs never materialized)
    conv_dt_kernel<<<NROWS / RROWS, 256, 0, stream>>>(xi, conv_w, conv_b, W_dt, b_dt, uT, dtT);

    // 4. segmented parallel scan -> res[b*S+s]  (depth 160 vs 2048)
    scan2_kernel<<<2, 512, 0, stream>>>(dtT, uT, A_log, res);

    // 5. GEMM2 (128^2 gemm_bt2, known-best): out = (4096*res[row]) * (g @ W_out^T)
    gemm_bt2<<<dim3(16, 32), 256, 0, stream>>>(g, wob, DINNER, out, res);
}

// Round 9
// 465.775 us; speedup vs baseline: 1.1179x; 1.1179x over previous
//
#include <hip/hip_runtime.h>
#include <hip/hip_bf16.h>
#include <math.h>

using bf16_t = __bf16;
using bf16x4 = __attribute__((ext_vector_type(4))) __bf16;
using bf16x8 = __attribute__((ext_vector_type(8))) __bf16;
using f32x4  = __attribute__((ext_vector_type(4))) float;

typedef __attribute__((address_space(1))) const void* gas_ptr;
typedef __attribute__((address_space(3))) void*       las_ptr;

// ---------------------------------------------------------------------------
// Problem constants
// ---------------------------------------------------------------------------
#define BATCH    2
#define SEQ      2048
#define DMODEL   2048
#define DINNER   4096
#define DSTATE   16
#define NROWS    (BATCH * SEQ)          // 4096

// ---------------------------------------------------------------------------
// merged fp32 -> bf16 cast: W_in, x, W_out, W_dt[:16]; 8 elem/thread
// ---------------------------------------------------------------------------
#define CAST_C0  (2 * DINNER * DMODEL / 8)   // W_in chunks  = 2097152
#define CAST_C1  (NROWS * DMODEL / 8)        // x chunks     = 1048576
#define CAST_C2  (DMODEL * DINNER / 8)       // W_out chunks = 1048576
#define CAST_C3  (DSTATE * DINNER / 8)       // W_dt[:16]    = 8192
#define CAST_BLOCKS ((CAST_C0 + CAST_C1 + CAST_C2 + CAST_C3) / 256)

__global__ __launch_bounds__(256)
void cast_all_kernel(const float* __restrict__ s0, bf16_t* __restrict__ d0,
                     const float* __restrict__ s1, bf16_t* __restrict__ d1,
                     const float* __restrict__ s2, bf16_t* __restrict__ d2,
                     const float* __restrict__ s3, bf16_t* __restrict__ d3)
{
    int i = blockIdx.x * 256 + threadIdx.x;
    const float* src; bf16_t* dst; int j;
    if (i < CAST_C0)                            { src = s0; dst = d0; j = i; }
    else if (i < CAST_C0 + CAST_C1)             { src = s1; dst = d1; j = i - CAST_C0; }
    else if (i < CAST_C0 + CAST_C1 + CAST_C2)   { src = s2; dst = d2; j = i - CAST_C0 - CAST_C1; }
    else                                        { src = s3; dst = d3; j = i - CAST_C0 - CAST_C1 - CAST_C2; }
    size_t off = (size_t)j * 8;
    float4 a = *(const float4*)(src + off);
    float4 b = *(const float4*)(src + off + 4);
    bf16x8 o;
    o[0] = (bf16_t)a.x; o[1] = (bf16_t)a.y; o[2] = (bf16_t)a.z; o[3] = (bf16_t)a.w;
    o[4] = (bf16_t)b.x; o[5] = (bf16_t)b.y; o[6] = (bf16_t)b.z; o[7] = (bf16_t)b.w;
    *(bf16x8*)(dst + off) = o;
}

// ---------------------------------------------------------------------------
// Schedule primitives. Ledger: R2/R3 counted-vmcnt null-to-negative;
// runtime LDS offsets wreck codegen; R4 8-MFMA phases pay 2x barrier cost;
// R7: 1-block/CU phase-split GEMM2 loses to 2-block/CU plain 128^2;
// R8: gemm1 half-grid split costs ~70us (exactly-1-round loses cross-round
// overlap; MfmaUtil 34.5->22.8) -> single launch. conv_dt was 118us at 11%
// occupancy / VGPR 164 -> split into conv_silu (streaming) + dt_mfma (GEMM).
// ---------------------------------------------------------------------------
#define GBAR()     asm volatile("s_barrier" ::: "memory")
#define WLGKM0()   asm volatile("s_waitcnt lgkmcnt(0)" ::: "memory")
#define WVM0()     asm volatile("s_waitcnt vmcnt(0)" ::: "memory")

#define MM(m, n, av, bv) \
    acc[m][n] = __builtin_amdgcn_mfma_f32_16x16x32_bf16(av, bv, acc[m][n], 0, 0, 0)

// ---------------------------------------------------------------------------
// GEMM1 (256x256 tile, BK=64, 8 waves = 2M x 4N, 4-phase schedule):
//   C = A(4096x2048) * B(8192x2048)^T ; col<4096 -> xi fp32, else sigmoid->g
//   (R1 exact: best measured -- 164 us, 833 TF)
// ---------------------------------------------------------------------------
#define MFMA_COL2(nA, nB, bA, bB)                                   \
    MM(0, nA, a0, bA); MM(0, nB, a0, bB); MM(1, nA, a1, bA); MM(1, nB, a1, bB); \
    MM(2, nA, a2, bA); MM(2, nB, a2, bB); MM(3, nA, a3, bA); MM(3, nB, a3, bB); \
    MM(4, nA, a4, bA); MM(4, nB, a4, bB); MM(5, nA, a5, bA); MM(5, nB, a5, bB); \
    MM(6, nA, a6, bA); MM(6, nB, a6, bB); MM(7, nA, a7, bA); MM(7, nB, a7, bB)

__global__ __launch_bounds__(512, 2)
void gemm1_256(const bf16_t* __restrict__ A, const bf16_t* __restrict__ B,
               float* __restrict__ outf, bf16_t* __restrict__ outg)
{
    constexpr int K  = DMODEL;   // 2048
    constexpr int NT = K / 64;   // 32 K-tiles

    __shared__ bf16_t As[2][256 * 64];   // 32 KiB per buffer
    __shared__ bf16_t Bs[2][256 * 64];   // total LDS = 128 KiB -> 1 block/CU

    const int t    = threadIdx.x;
    const int w    = t >> 6;          // wave 0..7
    const int lane = t & 63;
    const int wm   = w >> 2;          // 0..1  (M half: 128 rows)
    const int wn   = w & 3;           // 0..3  (N quarter: 64 cols)
    const int lo   = lane & 15;
    const int q    = lane >> 4;
    const int swz  = lo & 7;

    const int m0 = blockIdx.y * 256;
    const int n0 = blockIdx.x * 256;

    // staging lane geometry (proven scheme, SQ_LDS_BANK_CONFLICT == 0):
    const int r_l   = lane >> 3;
    const int cb    = (lane & 7) ^ r_l;
    const int laneg = r_l * K + cb * 8;          // lane offset in elements

    const bf16_t* Abase = A + (size_t)(m0 + w * 32) * K;
    const bf16_t* Bbase = B + (size_t)(n0 + w * 32) * K;

#define STAGE_A(BUF, kk) do {                                                  \
    _Pragma("unroll")                                                          \
    for (int c = 0; c < 4; ++c)                                                \
        __builtin_amdgcn_global_load_lds(                                      \
            (gas_ptr)(Abase + (kk) + c * 8 * K + laneg),                       \
            (las_ptr)&As[BUF][(w * 32 + c * 8) * 64], 16, 0, 0);               \
} while (0)
#define STAGE_B(BUF, kk) do {                                                  \
    _Pragma("unroll")                                                          \
    for (int c = 0; c < 4; ++c)                                                \
        __builtin_amdgcn_global_load_lds(                                      \
            (gas_ptr)(Bbase + (kk) + c * 8 * K + laneg),                       \
            (las_ptr)&Bs[BUF][(w * 32 + c * 8) * 64], 16, 0, 0);               \
} while (0)

    // fragment reads: row-swizzled col-block ((s*4+q) ^ (row&7))
#define LDA_F(BUF, m, s) \
    (*(const bf16x8*)&As[BUF][(wm * 128 + (m) * 16 + lo) * 64 + ((((s) * 4 + q) ^ swz) * 8)])
#define LDB_F(BUF, n, s) \
    (*(const bf16x8*)&Bs[BUF][(wn * 64  + (n) * 16 + lo) * 64 + ((((s) * 4 + q) ^ swz) * 8)])

    f32x4 acc[8][4];
#pragma unroll
    for (int i = 0; i < 8; ++i)
#pragma unroll
        for (int j = 0; j < 4; ++j) acc[i][j] = (f32x4){0.f, 0.f, 0.f, 0.f};

    // prologue: stage K-tile 0 into buffer 0, drain, barrier
    STAGE_A(0, 0);
    STAGE_B(0, 0);
    WVM0();
    GBAR();

#define TILE_STEP(CUR, NXT, tkv) do {                                          \
    const int  k1_  = ((tkv) + 1) * 64;                                        \
    const bool pre_ = ((tkv) + 1) < NT;                                        \
    bf16x8 a0, a1, a2, a3, a4, a5, a6, a7, b0, b1, b2, b3;                     \
    /* ---- sub0: A frags s0 + B n0..1 s0 ; stage A(t+1) ---- */               \
    a0 = LDA_F(CUR, 0, 0); a1 = LDA_F(CUR, 1, 0);                              \
    a2 = LDA_F(CUR, 2, 0); a3 = LDA_F(CUR, 3, 0);                              \
    a4 = LDA_F(CUR, 4, 0); a5 = LDA_F(CUR, 5, 0);                              \
    a6 = LDA_F(CUR, 6, 0); a7 = LDA_F(CUR, 7, 0);                              \
    b0 = LDB_F(CUR, 0, 0); b1 = LDB_F(CUR, 1, 0);                              \
    if (pre_) STAGE_A(NXT, k1_);                                               \
    GBAR(); WLGKM0();                                                          \
    __builtin_amdgcn_s_setprio(1);                                             \
    MFMA_COL2(0, 1, b0, b1);                                                   \
    __builtin_amdgcn_s_setprio(0);                                             \
    GBAR();                                                                    \
    /* ---- sub1: B n2..3 s0 ; stage B(t+1) ---- */                            \
    b2 = LDB_F(CUR, 2, 0); b3 = LDB_F(CUR, 3, 0);                              \
    if (pre_) STAGE_B(NXT, k1_);                                               \
    GBAR(); WLGKM0();                                                          \
    __builtin_amdgcn_s_setprio(1);                                             \
    MFMA_COL2(2, 3, b2, b3);                                                   \
    __builtin_amdgcn_s_setprio(0);                                             \
    GBAR();                                                                    \
    /* ---- sub2: A frags s1 + B n0..1 s1 ---- */                              \
    a0 = LDA_F(CUR, 0, 1); a1 = LDA_F(CUR, 1, 1);                              \
    a2 = LDA_F(CUR, 2, 1); a3 = LDA_F(CUR, 3, 1);                              \
    a4 = LDA_F(CUR, 4, 1); a5 = LDA_F(CUR, 5, 1);                              \
    a6 = LDA_F(CUR, 6, 1); a7 = LDA_F(CUR, 7, 1);                              \
    b0 = LDB_F(CUR, 0, 1); b1 = LDB_F(CUR, 1, 1);                              \
    GBAR(); WLGKM0();                                                          \
    __builtin_amdgcn_s_setprio(1);                                             \
    MFMA_COL2(0, 1, b0, b1);                                                   \
    __builtin_amdgcn_s_setprio(0);                                             \
    GBAR();                                                                    \
    /* ---- sub3: B n2..3 s1 ; drain stages (3 phases of flight) ---- */       \
    b2 = LDB_F(CUR, 2, 1); b3 = LDB_F(CUR, 3, 1);                              \
    GBAR(); WLGKM0();                                                          \
    __builtin_amdgcn_s_setprio(1);                                             \
    MFMA_COL2(2, 3, b2, b3);                                                   \
    __builtin_amdgcn_s_setprio(0);                                             \
    WVM0();                                                                    \
    GBAR();                                                                    \
} while (0)

#pragma unroll 1
    for (int tk = 0; tk < NT; tk += 2) {
        TILE_STEP(0, 1, tk);
        TILE_STEP(1, 0, tk + 1);
    }

    // epilogue: C/D layout col = lane&15, row = quad*4 + reg  [m89/m91]
#pragma unroll
    for (int m = 0; m < 8; ++m) {
        const int rbase = m0 + wm * 128 + m * 16 + q * 4;
#pragma unroll
        for (int n = 0; n < 4; ++n) {
            const int col = n0 + wn * 64 + n * 16 + lo;
#pragma unroll
            for (int rr = 0; rr < 4; ++rr) {
                float v   = acc[m][n][rr];
                int   row = rbase + rr;
                if (col < DINNER) {
                    outf[(size_t)row * DINNER + col] = v;              // xi fp32
                } else {
                    float sg = 1.f / (1.f + __expf(-v));               // sigmoid(gate)
                    outg[(size_t)row * DINNER + (col - DINNER)] = (bf16_t)sg;
                }
            }
        }
    }
}

// ---------------------------------------------------------------------------
// bf16 GEMM  C = A(MxK) * B(NxK)^T, 128x128 tile, BK=64, global_load_lds
// width=16 + XOR swizzle. GEMM2 (known-best config; 64 KiB LDS -> 2 blocks/CU
// gives cross-block overlap that hides barrier drains -- R7 A/B).
//   out = acc * (4096 * rowscale[row])
// ---------------------------------------------------------------------------
__global__ __launch_bounds__(256)
void gemm_bt2(const bf16_t* __restrict__ A, const bf16_t* __restrict__ B, int K,
              float* __restrict__ outf, const float* __restrict__ rowscale)
{
    constexpr int LDK = 64;            // unpadded: required by global_load_lds
    __shared__ bf16_t As[128 * LDK];
    __shared__ bf16_t Bs[128 * LDK];

    const int t    = threadIdx.x;
    const int m0   = blockIdx.y * 128;
    const int n0   = blockIdx.x * 128;
    const int w    = t >> 6;
    const int lane = t & 63;
    const int wr   = (w >> 1) * 64;
    const int wc   = (w & 1) * 64;
    const int lo   = lane & 15;
    const int q    = lane >> 4;

    const int r_l  = lane >> 3;
    const int cb   = (lane & 7) ^ r_l;
    const int laneA = (w * 32 + r_l) * K + cb * 8;
    const bf16_t* Abase = A + (size_t)m0 * K;
    const bf16_t* Bbase = B + (size_t)n0 * K;

    f32x4 acc[4][4];
#pragma unroll
    for (int i = 0; i < 4; ++i)
#pragma unroll
        for (int j = 0; j < 4; ++j) acc[i][j] = (f32x4){0.f, 0.f, 0.f, 0.f};

    for (int k0 = 0; k0 < K; k0 += 64) {
#pragma unroll
        for (int c = 0; c < 4; ++c) {
            const int uoff   = k0 + c * 8 * K;            // uniform (SGPR)
            const int lo_off = (w * 32 + c * 8) * LDK;    // wave-uniform LDS
            __builtin_amdgcn_global_load_lds((gas_ptr)(Abase + uoff + laneA),
                                             (las_ptr)&As[lo_off], 16, 0, 0);
            __builtin_amdgcn_global_load_lds((gas_ptr)(Bbase + uoff + laneA),
                                             (las_ptr)&Bs[lo_off], 16, 0, 0);
        }
        __syncthreads();

        const int swz = lo & 7;
#pragma unroll
        for (int ks = 0; ks < 2; ++ks) {
            const int kk = ((ks * 4 + q) ^ swz) * 8;
            bf16x8 af[4], bfv[4];
#pragma unroll
            for (int mi = 0; mi < 4; ++mi)
                af[mi] = *(const bf16x8*)&As[(wr + mi * 16 + lo) * LDK + kk];
#pragma unroll
            for (int ni = 0; ni < 4; ++ni)
                bfv[ni] = *(const bf16x8*)&Bs[(wc + ni * 16 + lo) * LDK + kk];
#pragma unroll
            for (int mi = 0; mi < 4; ++mi)
#pragma unroll
                for (int ni = 0; ni < 4; ++ni)
                    acc[mi][ni] = __builtin_amdgcn_mfma_f32_16x16x32_bf16(
                        af[mi], bfv[ni], acc[mi][ni], 0, 0, 0);
        }
        __syncthreads();
    }

#pragma unroll
    for (int mi = 0; mi < 4; ++mi) {
#pragma unroll
        for (int ni = 0; ni < 4; ++ni) {
            const int col   = n0 + wc + ni * 16 + lo;
            const int rbase = m0 + wr + mi * 16 + q * 4;
#pragma unroll
            for (int rr = 0; rr < 4; ++rr) {
                int row = rbase + rr;
                outf[(size_t)row * DMODEL + col] =
                    acc[mi][ni][rr] * (4096.0f * rowscale[row]);
            }
        }
    }
}

// ---------------------------------------------------------------------------
// conv_silu: depthwise causal conv(4) + SiLU -> xs (bf16) + u extraction
// (fp32). Streaming, low-VGPR (the R8 profile showed the fused conv_dt at
// VGPR=164 / 11% occupancy / 534 GB/s -- the 128-reg accumulator state was
// the killer; dt moved to an MFMA kernel).
// ---------------------------------------------------------------------------
#define RROWS 4
__global__ __launch_bounds__(256)
void conv_silu_kernel(const float* __restrict__ xi, const float* __restrict__ cw,
                      const float* __restrict__ cbias,
                      bf16_t* __restrict__ xs, float* __restrict__ uT)
{
    const int r0 = blockIdx.x * RROWS;          // 4 rows, same batch (SEQ%4==0)
    const int t  = threadIdx.x;
    const int s0 = r0 & (SEQ - 1);
    const int b  = r0 >> 11;

#pragma unroll
    for (int j = 0; j < 4; ++j) {
        const int c = t * 4 + j * 1024;
        float4 w0 = *(const float4*)(cw + (c + 0) * 4);
        float4 w1 = *(const float4*)(cw + (c + 1) * 4);
        float4 w2 = *(const float4*)(cw + (c + 2) * 4);
        float4 w3 = *(const float4*)(cw + (c + 3) * 4);
        float4 cbv = *(const float4*)(cbias + c);
        float4 xr[RROWS + 3];
#pragma unroll
        for (int i = 0; i < RROWS + 3; ++i) {
            int ss = s0 - 3 + i;
            if (ss >= 0)
                xr[i] = *(const float4*)(xi + (size_t)(r0 - 3 + i) * DINNER + c);
            else
                xr[i] = make_float4(0.f, 0.f, 0.f, 0.f);
        }
#pragma unroll
        for (int rr = 0; rr < RROWS; ++rr) {
            float4 a = xr[rr], bv = xr[rr + 1], cc = xr[rr + 2], d = xr[rr + 3];
            float v0 = cbv.x + w0.x * a.x + w0.y * bv.x + w0.z * cc.x + w0.w * d.x;
            float v1 = cbv.y + w1.x * a.y + w1.y * bv.y + w1.z * cc.y + w1.w * d.y;
            float v2 = cbv.z + w2.x * a.z + w2.y * bv.z + w2.z * cc.z + w2.w * d.z;
            float v3 = cbv.w + w3.x * a.w + w3.y * bv.w + w3.z * cc.w + w3.w * d.w;
            float o0 = v0 / (1.f + __expf(-v0));
            float o1 = v1 / (1.f + __expf(-v1));
            float o2 = v2 / (1.f + __expf(-v2));
            float o3 = v3 / (1.f + __expf(-v3));
            bf16x4 ov;
            ov[0] = (bf16_t)o0; ov[1] = (bf16_t)o1;
            ov[2] = (bf16_t)o2; ov[3] = (bf16_t)o3;
            *(bf16x4*)(xs + (size_t)(r0 + rr) * DINNER + c) = ov;
            if (j == 0 && t < 4) {                       // channels 0..15: u fp32
                uT[b * (DSTATE * SEQ) + (c + 0) * SEQ + (s0 + rr)] = o0;
                uT[b * (DSTATE * SEQ) + (c + 1) * SEQ + (s0 + rr)] = o1;
                uT[b * (DSTATE * SEQ) + (c + 2) * SEQ + (s0 + rr)] = o2;
                uT[b * (DSTATE * SEQ) + (c + 3) * SEQ + (s0 + rr)] = o3;
            }
        }
    }
}

// ---------------------------------------------------------------------------
// dt_mfma: dt = softplus(xs @ W_dt[:16]^T + b_dt) as a skinny MFMA GEMM
// (M=4096, N=16, K=4096). Block = 16 rows x 16 e; 4 waves split-K (1024
// each, 32 chained 16x16x32 MFMA); fragments loaded DIRECTLY from global
// (A: 16 xs rows; B: 16 wdtb rows -- L2-hot, 128 KB). LDS combine of the 4
// K-partials, + bias, softplus, write dtT[e][s]. Grid 256 blocks = 1/CU.
// Frag layout: A/B lane (lo,q) holds k = q*8..q*8+7 of the 32-slice;
// C/D col=lane&15 (e), row=(lane>>4)*4+reg  [m89/m91].
// ---------------------------------------------------------------------------
__global__ __launch_bounds__(256)
void dt_mfma_kernel(const bf16_t* __restrict__ xs, const bf16_t* __restrict__ wdtb,
                    const float* __restrict__ bdt, float* __restrict__ dtT)
{
    __shared__ float red[4][256];
    const int t    = threadIdx.x;
    const int w    = t >> 6;
    const int lane = t & 63;
    const int lo   = lane & 15;
    const int q    = lane >> 4;
    const int r0   = blockIdx.x * 16;

    const bf16_t* arow = xs   + (size_t)(r0 + lo) * DINNER + w * 1024 + q * 8;
    const bf16_t* brow = wdtb + (size_t)lo        * DINNER + w * 1024 + q * 8;

    f32x4 acc = (f32x4){0.f, 0.f, 0.f, 0.f};
#pragma unroll
    for (int kt = 0; kt < 32; ++kt) {
        bf16x8 a  = *(const bf16x8*)(arow + kt * 32);
        bf16x8 bv = *(const bf16x8*)(brow + kt * 32);
        acc = __builtin_amdgcn_mfma_f32_16x16x32_bf16(a, bv, acc, 0, 0, 0);
    }
#pragma unroll
    for (int i = 0; i < 4; ++i) red[w][lane * 4 + i] = acc[i];
    __syncthreads();

    {   // t == lane*4 + i
        const int ln  = t >> 2;                  // source lane 0..63
        const int i   = t & 3;                   // reg 0..3
        const int e   = ln & 15;
        const int row = r0 + (ln >> 4) * 4 + i;
        float v = red[0][t] + red[1][t] + red[2][t] + red[3][t] + bdt[e];
        float dtv = (v > 20.f) ? v : log1pf(__expf(v));
        dtT[(row >> 11) * (DSTATE * SEQ) + e * SEQ + (row & (SEQ - 1))] = dtv;
    }
}

// ---------------------------------------------------------------------------
// segmented parallel scan: 2 blocks (one per batch) x 512 threads
//   = 16 states x 32 segments of 64 steps.  Sequential depth 160 vs 2048.
//   (R6: -54 us vs the 64-thread serial version.)
// ---------------------------------------------------------------------------
__global__ __launch_bounds__(512)
void scan2_kernel(const float* __restrict__ dtT, const float* __restrict__ uT,
                  const float* __restrict__ A_log, float* __restrict__ result)
{
    __shared__ float cont[SEQ * 17];            // 139264 B
    __shared__ float segP[DSTATE][32];
    __shared__ float segH[DSTATE][32];
    __shared__ float hin[DSTATE][32];

    const int b   = blockIdx.x;
    const int t   = threadIdx.x;
    const int n   = t >> 5;                     // 0..15
    const int seg = t & 31;                     // 0..31
    const float An = -expf(A_log[n]);

    const float* dtp = dtT + b * (DSTATE * SEQ) + n * SEQ + seg * 64;
    const float* up  = uT  + b * (DSTATE * SEQ) + n * SEQ + seg * 64;

    // pass 1: (P, H) for this segment assuming h_in = 0
    float P = 1.f, H = 0.f;
    for (int i = 0; i < 64; i += 4) {
        float4 dv = *(const float4*)(dtp + i);
        float4 uv = *(const float4*)(up + i);
        float a;
        a = 1.f + dv.x; P *= a; H = H * a + uv.x;
        a = 1.f + dv.y; P *= a; H = H * a + uv.y;
        a = 1.f + dv.z; P *= a; H = H * a + uv.z;
        a = 1.f + dv.w; P *= a; H = H * a + uv.w;
    }
    segP[n][seg] = P;
    segH[n][seg] = H;
    __syncthreads();

    // exclusive affine prefix over 32 segments, serial per state
    if (t < DSTATE) {
        float h = 0.f;
#pragma unroll
        for (int j = 0; j < 32; ++j) {
            hin[t][j] = h;
            h = segP[t][j] * h + segH[t][j];
        }
    }
    __syncthreads();

    // pass 2: replay with correct h_in; write h*An (n-swizzled)
    {
        float h = hin[n][seg];
        const int nsw = (n + seg) & 15;
        for (int i = 0; i < 64; i += 4) {
            float4 dv = *(const float4*)(dtp + i);
            float4 uv = *(const float4*)(up + i);
            const int s = seg * 64 + i;
            h = h * (1.f + dv.x) + uv.x; cont[(s + 0) * 17 + nsw] = h * An;
            h = h * (1.f + dv.y) + uv.y; cont[(s + 1) * 17 + nsw] = h * An;
            h = h * (1.f + dv.z) + uv.z; cont[(s + 2) * 17 + nsw] = h * An;
            h = h * (1.f + dv.w) + uv.w; cont[(s + 3) * 17 + nsw] = h * An;
        }
    }
    __syncthreads();

    // reduce over the 16 states; lane stride 17 words -> conflict-free
#pragma unroll
    for (int k = 0; k < 4; ++k) {
        const int s = t + k * 512;
        float sum = 0.f;
#pragma unroll
        for (int j = 0; j < DSTATE; ++j) sum += cont[s * 17 + j];
        result[b * SEQ + s] = sum;
    }
}

// ---------------------------------------------------------------------------
// launch
// ---------------------------------------------------------------------------
extern "C" void kernel_launch(void* const* d_in, const int* in_sizes, int n_in,
                              void* d_out, int out_size, void* d_ws, size_t ws_size,
                              hipStream_t stream)
{
    const float* x      = (const float*)d_in[0];
    const float* W_in   = (const float*)d_in[1];
    const float* conv_w = (const float*)d_in[2];
    const float* conv_b = (const float*)d_in[3];
    const float* W_dt   = (const float*)d_in[4];
    const float* b_dt   = (const float*)d_in[5];
    const float* A_log  = (const float*)d_in[6];
    const float* W_out  = (const float*)d_in[7];
    float* out = (float*)d_out;

    const size_t MB = 1u << 20;
    char* w = (char*)d_ws;
    bf16_t* xb   = (bf16_t*)(w);                     // 16 MB
    bf16_t* wib  = (bf16_t*)(w + 16 * MB);           // 32 MB
    bf16_t* wob  = (bf16_t*)(w + 48 * MB);           // 16 MB
    float*  xi   = (float*) (w + 64 * MB);           // 64 MB
    bf16_t* g    = (bf16_t*)(w + 128 * MB);          // 32 MB
    float*  uT   = (float*) (w + 160 * MB);                      // 256 KB
    float*  dtT  = (float*) (w + 160 * MB + 262144);             // 256 KB
    float*  res  = (float*) (w + 160 * MB + 2 * 262144);         // 16 KB
    bf16_t* xs   = (bf16_t*)(w + 161 * MB);          // 32 MB
    bf16_t* wdtb = (bf16_t*)(w + 193 * MB);          // 128 KB

    // 1. merged casts to bf16 (W_in, x, W_out, W_dt[:16])
    cast_all_kernel<<<CAST_BLOCKS, 256, 0, stream>>>(W_in, wib, x, xb, W_out, wob,
                                                     W_dt, wdtb);

    // 2. GEMM1 (256^2, R1 schedule, single launch): x @ W_in^T -> xi | g
    gemm1_256<<<dim3(32, 16), 512, 0, stream>>>(xb, wib, xi, g);

    // 3a. conv + silu -> xs bf16, u fp32
    conv_silu_kernel<<<NROWS / RROWS, 256, 0, stream>>>(xi, conv_w, conv_b, xs, uT);

    // 3b. dt = softplus(xs @ W_dt[:16]^T + b) via MFMA
    dt_mfma_kernel<<<NROWS / 16, 256, 0, stream>>>(xs, wdtb, b_dt, dtT);

    // 4. segmented parallel scan -> res[b*S+s]
    scan2_kernel<<<2, 512, 0, stream>>>(dtT, uT, A_log, res);

    // 5. GEMM2 (128^2 gemm_bt2, known-best): out = (4096*res[row]) * (g @ W_out^T)
    gemm_bt2<<<dim3(16, 32), 256, 0, stream>>>(g, wob, DINNER, out, res);
}

// Round 10
// 453.755 us; speedup vs baseline: 1.1475x; 1.0265x over previous
//
#include <hip/hip_runtime.h>
#include <hip/hip_bf16.h>
#include <math.h>

using bf16_t = __bf16;
using bf16x4 = __attribute__((ext_vector_type(4))) __bf16;
using bf16x8 = __attribute__((ext_vector_type(8))) __bf16;
using f32x4  = __attribute__((ext_vector_type(4))) float;

typedef __attribute__((address_space(1))) const void* gas_ptr;
typedef __attribute__((address_space(3))) void*       las_ptr;

// ---------------------------------------------------------------------------
// Problem constants
// ---------------------------------------------------------------------------
#define BATCH    2
#define SEQ      2048
#define DMODEL   2048
#define DINNER   4096
#define DSTATE   16
#define NROWS    (BATCH * SEQ)          // 4096

// ---------------------------------------------------------------------------
// merged fp32 -> bf16 cast: W_in, x, W_out, W_dt[:16]; 8 elem/thread
// ---------------------------------------------------------------------------
#define CAST_C0  (2 * DINNER * DMODEL / 8)   // W_in chunks  = 2097152
#define CAST_C1  (NROWS * DMODEL / 8)        // x chunks     = 1048576
#define CAST_C2  (DMODEL * DINNER / 8)       // W_out chunks = 1048576
#define CAST_C3  (DSTATE * DINNER / 8)       // W_dt[:16]    = 8192
#define CAST_BLOCKS ((CAST_C0 + CAST_C1 + CAST_C2 + CAST_C3) / 256)

__global__ __launch_bounds__(256)
void cast_all_kernel(const float* __restrict__ s0, bf16_t* __restrict__ d0,
                     const float* __restrict__ s1, bf16_t* __restrict__ d1,
                     const float* __restrict__ s2, bf16_t* __restrict__ d2,
                     const float* __restrict__ s3, bf16_t* __restrict__ d3)
{
    int i = blockIdx.x * 256 + threadIdx.x;
    const float* src; bf16_t* dst; int j;
    if (i < CAST_C0)                            { src = s0; dst = d0; j = i; }
    else if (i < CAST_C0 + CAST_C1)             { src = s1; dst = d1; j = i - CAST_C0; }
    else if (i < CAST_C0 + CAST_C1 + CAST_C2)   { src = s2; dst = d2; j = i - CAST_C0 - CAST_C1; }
    else                                        { src = s3; dst = d3; j = i - CAST_C0 - CAST_C1 - CAST_C2; }
    size_t off = (size_t)j * 8;
    float4 a = *(const float4*)(src + off);
    float4 b = *(const float4*)(src + off + 4);
    bf16x8 o;
    o[0] = (bf16_t)a.x; o[1] = (bf16_t)a.y; o[2] = (bf16_t)a.z; o[3] = (bf16_t)a.w;
    o[4] = (bf16_t)b.x; o[5] = (bf16_t)b.y; o[6] = (bf16_t)b.z; o[7] = (bf16_t)b.w;
    *(bf16x8*)(dst + off) = o;
}

// ---------------------------------------------------------------------------
// Schedule primitives. Ledger: R2/R3 counted-vmcnt null-to-negative;
// runtime LDS offsets wreck codegen; R4 8-MFMA phases pay 2x barrier cost;
// R7: 1-block/CU phase-split GEMM2 loses to 2-block/CU plain 128^2;
// R8: gemm1 grid split costs ~70us (loses cross-round overlap);
// R9: conv_dt split into conv_silu + dt_mfma = -45us.
// R10: gemm2 gets R1's dbuf pipeline at its own 128^2 / 2-block/CU geometry.
// ---------------------------------------------------------------------------
#define GBAR()     asm volatile("s_barrier" ::: "memory")
#define WLGKM0()   asm volatile("s_waitcnt lgkmcnt(0)" ::: "memory")
#define WVM0()     asm volatile("s_waitcnt vmcnt(0)" ::: "memory")

#define MM(m, n, av, bv) \
    acc[m][n] = __builtin_amdgcn_mfma_f32_16x16x32_bf16(av, bv, acc[m][n], 0, 0, 0)

// ---------------------------------------------------------------------------
// GEMM1 (256x256 tile, BK=64, 8 waves = 2M x 4N, 4-phase schedule):
//   C = A(4096x2048) * B(8192x2048)^T ; col<4096 -> xi fp32, else sigmoid->g
//   (R1 exact: best measured -- 164 us, 833 TF)
// ---------------------------------------------------------------------------
#define MFMA_COL2(nA, nB, bA, bB)                                   \
    MM(0, nA, a0, bA); MM(0, nB, a0, bB); MM(1, nA, a1, bA); MM(1, nB, a1, bB); \
    MM(2, nA, a2, bA); MM(2, nB, a2, bB); MM(3, nA, a3, bA); MM(3, nB, a3, bB); \
    MM(4, nA, a4, bA); MM(4, nB, a4, bB); MM(5, nA, a5, bA); MM(5, nB, a5, bB); \
    MM(6, nA, a6, bA); MM(6, nB, a6, bB); MM(7, nA, a7, bA); MM(7, nB, a7, bB)

__global__ __launch_bounds__(512, 2)
void gemm1_256(const bf16_t* __restrict__ A, const bf16_t* __restrict__ B,
               float* __restrict__ outf, bf16_t* __restrict__ outg)
{
    constexpr int K  = DMODEL;   // 2048
    constexpr int NT = K / 64;   // 32 K-tiles

    __shared__ bf16_t As[2][256 * 64];   // 32 KiB per buffer
    __shared__ bf16_t Bs[2][256 * 64];   // total LDS = 128 KiB -> 1 block/CU

    const int t    = threadIdx.x;
    const int w    = t >> 6;          // wave 0..7
    const int lane = t & 63;
    const int wm   = w >> 2;          // 0..1  (M half: 128 rows)
    const int wn   = w & 3;           // 0..3  (N quarter: 64 cols)
    const int lo   = lane & 15;
    const int q    = lane >> 4;
    const int swz  = lo & 7;

    const int m0 = blockIdx.y * 256;
    const int n0 = blockIdx.x * 256;

    // staging lane geometry (proven scheme, SQ_LDS_BANK_CONFLICT == 0):
    const int r_l   = lane >> 3;
    const int cb    = (lane & 7) ^ r_l;
    const int laneg = r_l * K + cb * 8;          // lane offset in elements

    const bf16_t* Abase = A + (size_t)(m0 + w * 32) * K;
    const bf16_t* Bbase = B + (size_t)(n0 + w * 32) * K;

#define STAGE_A(BUF, kk) do {                                                  \
    _Pragma("unroll")                                                          \
    for (int c = 0; c < 4; ++c)                                                \
        __builtin_amdgcn_global_load_lds(                                      \
            (gas_ptr)(Abase + (kk) + c * 8 * K + laneg),                       \
            (las_ptr)&As[BUF][(w * 32 + c * 8) * 64], 16, 0, 0);               \
} while (0)
#define STAGE_B(BUF, kk) do {                                                  \
    _Pragma("unroll")                                                          \
    for (int c = 0; c < 4; ++c)                                                \
        __builtin_amdgcn_global_load_lds(                                      \
            (gas_ptr)(Bbase + (kk) + c * 8 * K + laneg),                       \
            (las_ptr)&Bs[BUF][(w * 32 + c * 8) * 64], 16, 0, 0);               \
} while (0)

    // fragment reads: row-swizzled col-block ((s*4+q) ^ (row&7))
#define LDA_F(BUF, m, s) \
    (*(const bf16x8*)&As[BUF][(wm * 128 + (m) * 16 + lo) * 64 + ((((s) * 4 + q) ^ swz) * 8)])
#define LDB_F(BUF, n, s) \
    (*(const bf16x8*)&Bs[BUF][(wn * 64  + (n) * 16 + lo) * 64 + ((((s) * 4 + q) ^ swz) * 8)])

    f32x4 acc[8][4];
#pragma unroll
    for (int i = 0; i < 8; ++i)
#pragma unroll
        for (int j = 0; j < 4; ++j) acc[i][j] = (f32x4){0.f, 0.f, 0.f, 0.f};

    // prologue: stage K-tile 0 into buffer 0, drain, barrier
    STAGE_A(0, 0);
    STAGE_B(0, 0);
    WVM0();
    GBAR();

#define TILE_STEP(CUR, NXT, tkv) do {                                          \
    const int  k1_  = ((tkv) + 1) * 64;                                        \
    const bool pre_ = ((tkv) + 1) < NT;                                        \
    bf16x8 a0, a1, a2, a3, a4, a5, a6, a7, b0, b1, b2, b3;                     \
    /* ---- sub0: A frags s0 + B n0..1 s0 ; stage A(t+1) ---- */               \
    a0 = LDA_F(CUR, 0, 0); a1 = LDA_F(CUR, 1, 0);                              \
    a2 = LDA_F(CUR, 2, 0); a3 = LDA_F(CUR, 3, 0);                              \
    a4 = LDA_F(CUR, 4, 0); a5 = LDA_F(CUR, 5, 0);                              \
    a6 = LDA_F(CUR, 6, 0); a7 = LDA_F(CUR, 7, 0);                              \
    b0 = LDB_F(CUR, 0, 0); b1 = LDB_F(CUR, 1, 0);                              \
    if (pre_) STAGE_A(NXT, k1_);                                               \
    GBAR(); WLGKM0();                                                          \
    __builtin_amdgcn_s_setprio(1);                                             \
    MFMA_COL2(0, 1, b0, b1);                                                   \
    __builtin_amdgcn_s_setprio(0);                                             \
    GBAR();                                                                    \
    /* ---- sub1: B n2..3 s0 ; stage B(t+1) ---- */                            \
    b2 = LDB_F(CUR, 2, 0); b3 = LDB_F(CUR, 3, 0);                              \
    if (pre_) STAGE_B(NXT, k1_);                                               \
    GBAR(); WLGKM0();                                                          \
    __builtin_amdgcn_s_setprio(1);                                             \
    MFMA_COL2(2, 3, b2, b3);                                                   \
    __builtin_amdgcn_s_setprio(0);                                             \
    GBAR();                                                                    \
    /* ---- sub2: A frags s1 + B n0..1 s1 ---- */                              \
    a0 = LDA_F(CUR, 0, 1); a1 = LDA_F(CUR, 1, 1);                              \
    a2 = LDA_F(CUR, 2, 1); a3 = LDA_F(CUR, 3, 1);                              \
    a4 = LDA_F(CUR, 4, 1); a5 = LDA_F(CUR, 5, 1);                              \
    a6 = LDA_F(CUR, 6, 1); a7 = LDA_F(CUR, 7, 1);                              \
    b0 = LDB_F(CUR, 0, 1); b1 = LDB_F(CUR, 1, 1);                              \
    GBAR(); WLGKM0();                                                          \
    __builtin_amdgcn_s_setprio(1);                                             \
    MFMA_COL2(0, 1, b0, b1);                                                   \
    __builtin_amdgcn_s_setprio(0);                                             \
    GBAR();                                                                    \
    /* ---- sub3: B n2..3 s1 ; drain stages (3 phases of flight) ---- */       \
    b2 = LDB_F(CUR, 2, 1); b3 = LDB_F(CUR, 3, 1);                              \
    GBAR(); WLGKM0();                                                          \
    __builtin_amdgcn_s_setprio(1);                                             \
    MFMA_COL2(2, 3, b2, b3);                                                   \
    __builtin_amdgcn_s_setprio(0);                                             \
    WVM0();                                                                    \
    GBAR();                                                                    \
} while (0)

#pragma unroll 1
    for (int tk = 0; tk < NT; tk += 2) {
        TILE_STEP(0, 1, tk);
        TILE_STEP(1, 0, tk + 1);
    }

    // epilogue: C/D layout col = lane&15, row = quad*4 + reg  [m89/m91]
#pragma unroll
    for (int m = 0; m < 8; ++m) {
        const int rbase = m0 + wm * 128 + m * 16 + q * 4;
#pragma unroll
        for (int n = 0; n < 4; ++n) {
            const int col = n0 + wn * 64 + n * 16 + lo;
#pragma unroll
            for (int rr = 0; rr < 4; ++rr) {
                float v   = acc[m][n][rr];
                int   row = rbase + rr;
                if (col < DINNER) {
                    outf[(size_t)row * DINNER + col] = v;              // xi fp32
                } else {
                    float sg = 1.f / (1.f + __expf(-v));               // sigmoid(gate)
                    outg[(size_t)row * DINNER + (col - DINNER)] = (bf16_t)sg;
                }
            }
        }
    }
}

// ---------------------------------------------------------------------------
// GEMM2 gemm2_db (128x128 tile, BK=64, 4 waves, double-buffered 2-phase
// pipeline): out = (4096 * rowscale[row]) * ( g @ W_out^T ), K=4096.
// Keeps gemm_bt2's winning geometry (grid 512 = 2 blocks/CU; LDS 64 KiB
// still allows 2 blocks) but replaces the serial stage->drain->compute loop
// with R1's placement: stage A+B(t+1) into NXT during phase0's MFMA, single
// vmcnt(0) drain at end of phase1 (~1.5 phases flight + cross-block overlap).
// 16-MFMA clusters = gemm1's proven barrier:MFMA ratio (R4 lesson).
// ---------------------------------------------------------------------------
#define MFMA_G16()                                                  \
    MM(0, 0, a0, b0); MM(0, 1, a0, b1); MM(1, 0, a1, b0); MM(1, 1, a1, b1); \
    MM(2, 0, a2, b0); MM(2, 1, a2, b1); MM(3, 0, a3, b0); MM(3, 1, a3, b1); \
    MM(0, 2, a0, b2); MM(0, 3, a0, b3); MM(1, 2, a1, b2); MM(1, 3, a1, b3); \
    MM(2, 2, a2, b2); MM(2, 3, a2, b3); MM(3, 2, a3, b2); MM(3, 3, a3, b3)

__global__ __launch_bounds__(256)
void gemm2_db(const bf16_t* __restrict__ A, const bf16_t* __restrict__ B,
              float* __restrict__ outf, const float* __restrict__ rowscale)
{
    constexpr int K  = DINNER;   // 4096
    constexpr int NT = K / 64;   // 64 K-tiles

    __shared__ bf16_t As2[2][128 * 64];   // 16 KiB per buffer
    __shared__ bf16_t Bs2[2][128 * 64];   // 64 KiB total -> 2 blocks/CU

    const int t    = threadIdx.x;
    const int w    = t >> 6;
    const int lane = t & 63;
    const int wr   = (w >> 1) * 64;
    const int wc   = (w & 1) * 64;
    const int lo   = lane & 15;
    const int q    = lane >> 4;
    const int swz  = lo & 7;

    const int m0 = blockIdx.y * 128;
    const int n0 = blockIdx.x * 128;

    const int r_l   = lane >> 3;
    const int cb    = (lane & 7) ^ r_l;
    const int laneg = r_l * K + cb * 8;

    const bf16_t* Abase = A + (size_t)(m0 + w * 32) * K;
    const bf16_t* Bbase = B + (size_t)(n0 + w * 32) * K;

#define ST2A(BUF, kk) do {                                                     \
    _Pragma("unroll")                                                          \
    for (int c = 0; c < 4; ++c)                                                \
        __builtin_amdgcn_global_load_lds(                                      \
            (gas_ptr)(Abase + (kk) + c * 8 * K + laneg),                       \
            (las_ptr)&As2[BUF][(w * 32 + c * 8) * 64], 16, 0, 0);              \
} while (0)
#define ST2B(BUF, kk) do {                                                     \
    _Pragma("unroll")                                                          \
    for (int c = 0; c < 4; ++c)                                                \
        __builtin_amdgcn_global_load_lds(                                      \
            (gas_ptr)(Bbase + (kk) + c * 8 * K + laneg),                       \
            (las_ptr)&Bs2[BUF][(w * 32 + c * 8) * 64], 16, 0, 0);              \
} while (0)

#define LD2A(BUF, m, s) \
    (*(const bf16x8*)&As2[BUF][(wr + (m) * 16 + lo) * 64 + ((((s) * 4 + q) ^ swz) * 8)])
#define LD2B(BUF, n, s) \
    (*(const bf16x8*)&Bs2[BUF][(wc + (n) * 16 + lo) * 64 + ((((s) * 4 + q) ^ swz) * 8)])

    f32x4 acc[4][4];
#pragma unroll
    for (int i = 0; i < 4; ++i)
#pragma unroll
        for (int j = 0; j < 4; ++j) acc[i][j] = (f32x4){0.f, 0.f, 0.f, 0.f};

    // prologue
    ST2A(0, 0);
    ST2B(0, 0);
    WVM0();
    GBAR();

#define G2STEP(CUR, NXT, tkv) do {                                             \
    const int  k1_  = ((tkv) + 1) * 64;                                        \
    const bool pre_ = ((tkv) + 1) < NT;                                        \
    bf16x8 a0, a1, a2, a3, b0, b1, b2, b3;                                     \
    /* ---- phase0: all frags kk-slice 0 ; stage A+B(t+1) -> NXT ---- */       \
    a0 = LD2A(CUR, 0, 0); a1 = LD2A(CUR, 1, 0);                                \
    a2 = LD2A(CUR, 2, 0); a3 = LD2A(CUR, 3, 0);                                \
    b0 = LD2B(CUR, 0, 0); b1 = LD2B(CUR, 1, 0);                                \
    b2 = LD2B(CUR, 2, 0); b3 = LD2B(CUR, 3, 0);                                \
    if (pre_) { ST2A(NXT, k1_); ST2B(NXT, k1_); }                              \
    GBAR(); WLGKM0();                                                          \
    __builtin_amdgcn_s_setprio(1);                                             \
    MFMA_G16();                                                                \
    __builtin_amdgcn_s_setprio(0);                                             \
    GBAR();                                                                    \
    /* ---- phase1: all frags kk-slice 1 ; drain stages ---- */                \
    a0 = LD2A(CUR, 0, 1); a1 = LD2A(CUR, 1, 1);                                \
    a2 = LD2A(CUR, 2, 1); a3 = LD2A(CUR, 3, 1);                                \
    b0 = LD2B(CUR, 0, 1); b1 = LD2B(CUR, 1, 1);                                \
    b2 = LD2B(CUR, 2, 1); b3 = LD2B(CUR, 3, 1);                                \
    GBAR(); WLGKM0();                                                          \
    __builtin_amdgcn_s_setprio(1);                                             \
    MFMA_G16();                                                                \
    __builtin_amdgcn_s_setprio(0);                                             \
    WVM0();                                                                    \
    GBAR();                                                                    \
} while (0)

#pragma unroll 1
    for (int tk = 0; tk < NT; tk += 2) {
        G2STEP(0, 1, tk);
        G2STEP(1, 0, tk + 1);
    }

    // epilogue: out = acc * (4096 * rowscale[row])
#pragma unroll
    for (int mi = 0; mi < 4; ++mi) {
#pragma unroll
        for (int ni = 0; ni < 4; ++ni) {
            const int col   = n0 + wc + ni * 16 + lo;
            const int rbase = m0 + wr + mi * 16 + q * 4;
#pragma unroll
            for (int rr = 0; rr < 4; ++rr) {
                int row = rbase + rr;
                outf[(size_t)row * DMODEL + col] =
                    acc[mi][ni][rr] * (4096.0f * rowscale[row]);
            }
        }
    }
}

// ---------------------------------------------------------------------------
// conv_silu: depthwise causal conv(4) + SiLU -> xs (bf16) + u extraction
// (fp32). Streaming, low-VGPR (R8: fused conv_dt was 118us @ VGPR 164 /
// 11% occupancy; splitting dt out fixed it -- R9: -45us total).
// ---------------------------------------------------------------------------
#define RROWS 4
__global__ __launch_bounds__(256)
void conv_silu_kernel(const float* __restrict__ xi, const float* __restrict__ cw,
                      const float* __restrict__ cbias,
                      bf16_t* __restrict__ xs, float* __restrict__ uT)
{
    const int r0 = blockIdx.x * RROWS;          // 4 rows, same batch (SEQ%4==0)
    const int t  = threadIdx.x;
    const int s0 = r0 & (SEQ - 1);
    const int b  = r0 >> 11;

#pragma unroll
    for (int j = 0; j < 4; ++j) {
        const int c = t * 4 + j * 1024;
        float4 w0 = *(const float4*)(cw + (c + 0) * 4);
        float4 w1 = *(const float4*)(cw + (c + 1) * 4);
        float4 w2 = *(const float4*)(cw + (c + 2) * 4);
        float4 w3 = *(const float4*)(cw + (c + 3) * 4);
        float4 cbv = *(const float4*)(cbias + c);
        float4 xr[RROWS + 3];
#pragma unroll
        for (int i = 0; i < RROWS + 3; ++i) {
            int ss = s0 - 3 + i;
            if (ss >= 0)
                xr[i] = *(const float4*)(xi + (size_t)(r0 - 3 + i) * DINNER + c);
            else
                xr[i] = make_float4(0.f, 0.f, 0.f, 0.f);
        }
#pragma unroll
        for (int rr = 0; rr < RROWS; ++rr) {
            float4 a = xr[rr], bv = xr[rr + 1], cc = xr[rr + 2], d = xr[rr + 3];
            float v0 = cbv.x + w0.x * a.x + w0.y * bv.x + w0.z * cc.x + w0.w * d.x;
            float v1 = cbv.y + w1.x * a.y + w1.y * bv.y + w1.z * cc.y + w1.w * d.y;
            float v2 = cbv.z + w2.x * a.z + w2.y * bv.z + w2.z * cc.z + w2.w * d.z;
            float v3 = cbv.w + w3.x * a.w + w3.y * bv.w + w3.z * cc.w + w3.w * d.w;
            float o0 = v0 / (1.f + __expf(-v0));
            float o1 = v1 / (1.f + __expf(-v1));
            float o2 = v2 / (1.f + __expf(-v2));
            float o3 = v3 / (1.f + __expf(-v3));
            bf16x4 ov;
            ov[0] = (bf16_t)o0; ov[1] = (bf16_t)o1;
            ov[2] = (bf16_t)o2; ov[3] = (bf16_t)o3;
            *(bf16x4*)(xs + (size_t)(r0 + rr) * DINNER + c) = ov;
            if (j == 0 && t < 4) {                       // channels 0..15: u fp32
                uT[b * (DSTATE * SEQ) + (c + 0) * SEQ + (s0 + rr)] = o0;
                uT[b * (DSTATE * SEQ) + (c + 1) * SEQ + (s0 + rr)] = o1;
                uT[b * (DSTATE * SEQ) + (c + 2) * SEQ + (s0 + rr)] = o2;
                uT[b * (DSTATE * SEQ) + (c + 3) * SEQ + (s0 + rr)] = o3;
            }
        }
    }
}

// ---------------------------------------------------------------------------
// dt_mfma: dt = softplus(xs @ W_dt[:16]^T + b_dt) as a skinny MFMA GEMM
// (M=4096, N=16, K=4096). Block = 16 rows x 16 e; 4 waves split-K; fragments
// direct from global (L2-hot). Grid 256 = 1/CU.
// ---------------------------------------------------------------------------
__global__ __launch_bounds__(256)
void dt_mfma_kernel(const bf16_t* __restrict__ xs, const bf16_t* __restrict__ wdtb,
                    const float* __restrict__ bdt, float* __restrict__ dtT)
{
    __shared__ float red[4][256];
    const int t    = threadIdx.x;
    const int w    = t >> 6;
    const int lane = t & 63;
    const int lo   = lane & 15;
    const int q    = lane >> 4;
    const int r0   = blockIdx.x * 16;

    const bf16_t* arow = xs   + (size_t)(r0 + lo) * DINNER + w * 1024 + q * 8;
    const bf16_t* brow = wdtb + (size_t)lo        * DINNER + w * 1024 + q * 8;

    f32x4 acc = (f32x4){0.f, 0.f, 0.f, 0.f};
#pragma unroll
    for (int kt = 0; kt < 32; ++kt) {
        bf16x8 a  = *(const bf16x8*)(arow + kt * 32);
        bf16x8 bv = *(const bf16x8*)(brow + kt * 32);
        acc = __builtin_amdgcn_mfma_f32_16x16x32_bf16(a, bv, acc, 0, 0, 0);
    }
#pragma unroll
    for (int i = 0; i < 4; ++i) red[w][lane * 4 + i] = acc[i];
    __syncthreads();

    {   // t == lane*4 + i
        const int ln  = t >> 2;                  // source lane 0..63
        const int i   = t & 3;                   // reg 0..3
        const int e   = ln & 15;
        const int row = r0 + (ln >> 4) * 4 + i;
        float v = red[0][t] + red[1][t] + red[2][t] + red[3][t] + bdt[e];
        float dtv = (v > 20.f) ? v : log1pf(__expf(v));
        dtT[(row >> 11) * (DSTATE * SEQ) + e * SEQ + (row & (SEQ - 1))] = dtv;
    }
}

// ---------------------------------------------------------------------------
// segmented parallel scan: 2 blocks (one per batch) x 512 threads
//   = 16 states x 32 segments of 64 steps.  Sequential depth 160 vs 2048.
// ---------------------------------------------------------------------------
__global__ __launch_bounds__(512)
void scan2_kernel(const float* __restrict__ dtT, const float* __restrict__ uT,
                  const float* __restrict__ A_log, float* __restrict__ result)
{
    __shared__ float cont[SEQ * 17];            // 139264 B
    __shared__ float segP[DSTATE][32];
    __shared__ float segH[DSTATE][32];
    __shared__ float hin[DSTATE][32];

    const int b   = blockIdx.x;
    const int t   = threadIdx.x;
    const int n   = t >> 5;                     // 0..15
    const int seg = t & 31;                     // 0..31
    const float An = -expf(A_log[n]);

    const float* dtp = dtT + b * (DSTATE * SEQ) + n * SEQ + seg * 64;
    const float* up  = uT  + b * (DSTATE * SEQ) + n * SEQ + seg * 64;

    // pass 1: (P, H) for this segment assuming h_in = 0
    float P = 1.f, H = 0.f;
    for (int i = 0; i < 64; i += 4) {
        float4 dv = *(const float4*)(dtp + i);
        float4 uv = *(const float4*)(up + i);
        float a;
        a = 1.f + dv.x; P *= a; H = H * a + uv.x;
        a = 1.f + dv.y; P *= a; H = H * a + uv.y;
        a = 1.f + dv.z; P *= a; H = H * a + uv.z;
        a = 1.f + dv.w; P *= a; H = H * a + uv.w;
    }
    segP[n][seg] = P;
    segH[n][seg] = H;
    __syncthreads();

    // exclusive affine prefix over 32 segments, serial per state
    if (t < DSTATE) {
        float h = 0.f;
#pragma unroll
        for (int j = 0; j < 32; ++j) {
            hin[t][j] = h;
            h = segP[t][j] * h + segH[t][j];
        }
    }
    __syncthreads();

    // pass 2: replay with correct h_in; write h*An (n-swizzled)
    {
        float h = hin[n][seg];
        const int nsw = (n + seg) & 15;
        for (int i = 0; i < 64; i += 4) {
            float4 dv = *(const float4*)(dtp + i);
            float4 uv = *(const float4*)(up + i);
            const int s = seg * 64 + i;
            h = h * (1.f + dv.x) + uv.x; cont[(s + 0) * 17 + nsw] = h * An;
            h = h * (1.f + dv.y) + uv.y; cont[(s + 1) * 17 + nsw] = h * An;
            h = h * (1.f + dv.z) + uv.z; cont[(s + 2) * 17 + nsw] = h * An;
            h = h * (1.f + dv.w) + uv.w; cont[(s + 3) * 17 + nsw] = h * An;
        }
    }
    __syncthreads();

    // reduce over the 16 states; lane stride 17 words -> conflict-free
#pragma unroll
    for (int k = 0; k < 4; ++k) {
        const int s = t + k * 512;
        float sum = 0.f;
#pragma unroll
        for (int j = 0; j < DSTATE; ++j) sum += cont[s * 17 + j];
        result[b * SEQ + s] = sum;
    }
}

// ---------------------------------------------------------------------------
// launch
// ---------------------------------------------------------------------------
extern "C" void kernel_launch(void* const* d_in, const int* in_sizes, int n_in,
                              void* d_out, int out_size, void* d_ws, size_t ws_size,
                              hipStream_t stream)
{
    const float* x      = (const float*)d_in[0];
    const float* W_in   = (const float*)d_in[1];
    const float* conv_w = (const float*)d_in[2];
    const float* conv_b = (const float*)d_in[3];
    const float* W_dt   = (const float*)d_in[4];
    const float* b_dt   = (const float*)d_in[5];
    const float* A_log  = (const float*)d_in[6];
    const float* W_out  = (const float*)d_in[7];
    float* out = (float*)d_out;

    const size_t MB = 1u << 20;
    char* w = (char*)d_ws;
    bf16_t* xb   = (bf16_t*)(w);                     // 16 MB
    bf16_t* wib  = (bf16_t*)(w + 16 * MB);           // 32 MB
    bf16_t* wob  = (bf16_t*)(w + 48 * MB);           // 16 MB
    float*  xi   = (float*) (w + 64 * MB);           // 64 MB
    bf16_t* g    = (bf16_t*)(w + 128 * MB);          // 32 MB
    float*  uT   = (float*) (w + 160 * MB);                      // 256 KB
    float*  dtT  = (float*) (w + 160 * MB + 262144);             // 256 KB
    float*  res  = (float*) (w + 160 * MB + 2 * 262144);         // 16 KB
    bf16_t* xs   = (bf16_t*)(w + 161 * MB);          // 32 MB
    bf16_t* wdtb = (bf16_t*)(w + 193 * MB);          // 128 KB

    // 1. merged casts to bf16 (W_in, x, W_out, W_dt[:16])
    cast_all_kernel<<<CAST_BLOCKS, 256, 0, stream>>>(W_in, wib, x, xb, W_out, wob,
                                                     W_dt, wdtb);

    // 2. GEMM1 (256^2, R1 schedule): x @ W_in^T -> xi fp32 | g bf16
    gemm1_256<<<dim3(32, 16), 512, 0, stream>>>(xb, wib, xi, g);

    // 3a. conv + silu -> xs bf16, u fp32
    conv_silu_kernel<<<NROWS / RROWS, 256, 0, stream>>>(xi, conv_w, conv_b, xs, uT);

    // 3b. dt = softplus(xs @ W_dt[:16]^T + b) via MFMA
    dt_mfma_kernel<<<NROWS / 16, 256, 0, stream>>>(xs, wdtb, b_dt, dtT);

    // 4. segmented parallel scan -> res[b*S+s]
    scan2_kernel<<<2, 512, 0, stream>>>(dtT, uT, A_log, res);

    // 5. GEMM2 (gemm2_db: dbuf-pipelined 128^2, 2 blocks/CU)
    gemm2_db<<<dim3(16, 32), 256, 0, stream>>>(g, wob, out, res);
}

// Round 11
// 447.111 us; speedup vs baseline: 1.1645x; 1.0149x over previous
//
#include <hip/hip_runtime.h>
#include <hip/hip_bf16.h>
#include <math.h>

using bf16_t = __bf16;
using bf16x4 = __attribute__((ext_vector_type(4))) __bf16;
using bf16x8 = __attribute__((ext_vector_type(8))) __bf16;
using f32x4  = __attribute__((ext_vector_type(4))) float;

typedef __attribute__((address_space(1))) const void* gas_ptr;
typedef __attribute__((address_space(3))) void*       las_ptr;

// ---------------------------------------------------------------------------
// Problem constants
// ---------------------------------------------------------------------------
#define BATCH    2
#define SEQ      2048
#define DMODEL   2048
#define DINNER   4096
#define DSTATE   16
#define NROWS    (BATCH * SEQ)          // 4096

// ---------------------------------------------------------------------------
// merged fp32 -> bf16 cast: W_in, x, W_out, W_dt[:16]; 8 elem/thread
// ---------------------------------------------------------------------------
#define CAST_C0  (2 * DINNER * DMODEL / 8)   // W_in chunks  = 2097152
#define CAST_C1  (NROWS * DMODEL / 8)        // x chunks     = 1048576
#define CAST_C2  (DMODEL * DINNER / 8)       // W_out chunks = 1048576
#define CAST_C3  (DSTATE * DINNER / 8)       // W_dt[:16]    = 8192
#define CAST_BLOCKS ((CAST_C0 + CAST_C1 + CAST_C2 + CAST_C3) / 256)

__global__ __launch_bounds__(256)
void cast_all_kernel(const float* __restrict__ s0, bf16_t* __restrict__ d0,
                     const float* __restrict__ s1, bf16_t* __restrict__ d1,
                     const float* __restrict__ s2, bf16_t* __restrict__ d2,
                     const float* __restrict__ s3, bf16_t* __restrict__ d3)
{
    int i = blockIdx.x * 256 + threadIdx.x;
    const float* src; bf16_t* dst; int j;
    if (i < CAST_C0)                            { src = s0; dst = d0; j = i; }
    else if (i < CAST_C0 + CAST_C1)             { src = s1; dst = d1; j = i - CAST_C0; }
    else if (i < CAST_C0 + CAST_C1 + CAST_C2)   { src = s2; dst = d2; j = i - CAST_C0 - CAST_C1; }
    else                                        { src = s3; dst = d3; j = i - CAST_C0 - CAST_C1 - CAST_C2; }
    size_t off = (size_t)j * 8;
    float4 a = *(const float4*)(src + off);
    float4 b = *(const float4*)(src + off + 4);
    bf16x8 o;
    o[0] = (bf16_t)a.x; o[1] = (bf16_t)a.y; o[2] = (bf16_t)a.z; o[3] = (bf16_t)a.w;
    o[4] = (bf16_t)b.x; o[5] = (bf16_t)b.y; o[6] = (bf16_t)b.z; o[7] = (bf16_t)b.w;
    *(bf16x8*)(dst + off) = o;
}

// ---------------------------------------------------------------------------
// Schedule primitives. Ledger: R2/R3 counted-vmcnt null-to-negative;
// runtime LDS offsets wreck codegen; R4 8-MFMA phases pay 2x barrier cost;
// R7: 1-block/CU phase-split GEMM2 loses to 2-block/CU plain 128^2;
// R8: gemm1 grid split costs ~70us; R9: conv_dt split = -45us;
// R10: gemm2_db dbuf pipeline = -12..18us. gemm1 schedule CLOSED: reg file
// is at the 256/wave ceiling (128 VGPR + 128 AGPR acc) -- fragment
// double-buffering (the m201 overlap mechanism) cannot fit.
// R11: xi -> bf16 (halves gemm1 write + conv read); conv RROWS 4->8.
// ---------------------------------------------------------------------------
#define GBAR()     asm volatile("s_barrier" ::: "memory")
#define WLGKM0()   asm volatile("s_waitcnt lgkmcnt(0)" ::: "memory")
#define WVM0()     asm volatile("s_waitcnt vmcnt(0)" ::: "memory")

#define MM(m, n, av, bv) \
    acc[m][n] = __builtin_amdgcn_mfma_f32_16x16x32_bf16(av, bv, acc[m][n], 0, 0, 0)

// ---------------------------------------------------------------------------
// GEMM1 (256x256 tile, BK=64, 8 waves = 2M x 4N, 4-phase schedule):
//   C = A(4096x2048) * B(8192x2048)^T ; col<4096 -> xi bf16, else sigmoid->g
// ---------------------------------------------------------------------------
#define MFMA_COL2(nA, nB, bA, bB)                                   \
    MM(0, nA, a0, bA); MM(0, nB, a0, bB); MM(1, nA, a1, bA); MM(1, nB, a1, bB); \
    MM(2, nA, a2, bA); MM(2, nB, a2, bB); MM(3, nA, a3, bA); MM(3, nB, a3, bB); \
    MM(4, nA, a4, bA); MM(4, nB, a4, bB); MM(5, nA, a5, bA); MM(5, nB, a5, bB); \
    MM(6, nA, a6, bA); MM(6, nB, a6, bB); MM(7, nA, a7, bA); MM(7, nB, a7, bB)

__global__ __launch_bounds__(512, 2)
void gemm1_256(const bf16_t* __restrict__ A, const bf16_t* __restrict__ B,
               bf16_t* __restrict__ outxi, bf16_t* __restrict__ outg)
{
    constexpr int K  = DMODEL;   // 2048
    constexpr int NT = K / 64;   // 32 K-tiles

    __shared__ bf16_t As[2][256 * 64];   // 32 KiB per buffer
    __shared__ bf16_t Bs[2][256 * 64];   // total LDS = 128 KiB -> 1 block/CU

    const int t    = threadIdx.x;
    const int w    = t >> 6;          // wave 0..7
    const int lane = t & 63;
    const int wm   = w >> 2;          // 0..1  (M half: 128 rows)
    const int wn   = w & 3;           // 0..3  (N quarter: 64 cols)
    const int lo   = lane & 15;
    const int q    = lane >> 4;
    const int swz  = lo & 7;

    const int m0 = blockIdx.y * 256;
    const int n0 = blockIdx.x * 256;

    // staging lane geometry (proven scheme, SQ_LDS_BANK_CONFLICT == 0):
    const int r_l   = lane >> 3;
    const int cb    = (lane & 7) ^ r_l;
    const int laneg = r_l * K + cb * 8;          // lane offset in elements

    const bf16_t* Abase = A + (size_t)(m0 + w * 32) * K;
    const bf16_t* Bbase = B + (size_t)(n0 + w * 32) * K;

#define STAGE_A(BUF, kk) do {                                                  \
    _Pragma("unroll")                                                          \
    for (int c = 0; c < 4; ++c)                                                \
        __builtin_amdgcn_global_load_lds(                                      \
            (gas_ptr)(Abase + (kk) + c * 8 * K + laneg),                       \
            (las_ptr)&As[BUF][(w * 32 + c * 8) * 64], 16, 0, 0);               \
} while (0)
#define STAGE_B(BUF, kk) do {                                                  \
    _Pragma("unroll")                                                          \
    for (int c = 0; c < 4; ++c)                                                \
        __builtin_amdgcn_global_load_lds(                                      \
            (gas_ptr)(Bbase + (kk) + c * 8 * K + laneg),                       \
            (las_ptr)&Bs[BUF][(w * 32 + c * 8) * 64], 16, 0, 0);               \
} while (0)

    // fragment reads: row-swizzled col-block ((s*4+q) ^ (row&7))
#define LDA_F(BUF, m, s) \
    (*(const bf16x8*)&As[BUF][(wm * 128 + (m) * 16 + lo) * 64 + ((((s) * 4 + q) ^ swz) * 8)])
#define LDB_F(BUF, n, s) \
    (*(const bf16x8*)&Bs[BUF][(wn * 64  + (n) * 16 + lo) * 64 + ((((s) * 4 + q) ^ swz) * 8)])

    f32x4 acc[8][4];
#pragma unroll
    for (int i = 0; i < 8; ++i)
#pragma unroll
        for (int j = 0; j < 4; ++j) acc[i][j] = (f32x4){0.f, 0.f, 0.f, 0.f};

    // prologue: stage K-tile 0 into buffer 0, drain, barrier
    STAGE_A(0, 0);
    STAGE_B(0, 0);
    WVM0();
    GBAR();

#define TILE_STEP(CUR, NXT, tkv) do {                                          \
    const int  k1_  = ((tkv) + 1) * 64;                                        \
    const bool pre_ = ((tkv) + 1) < NT;                                        \
    bf16x8 a0, a1, a2, a3, a4, a5, a6, a7, b0, b1, b2, b3;                     \
    /* ---- sub0: A frags s0 + B n0..1 s0 ; stage A(t+1) ---- */               \
    a0 = LDA_F(CUR, 0, 0); a1 = LDA_F(CUR, 1, 0);                              \
    a2 = LDA_F(CUR, 2, 0); a3 = LDA_F(CUR, 3, 0);                              \
    a4 = LDA_F(CUR, 4, 0); a5 = LDA_F(CUR, 5, 0);                              \
    a6 = LDA_F(CUR, 6, 0); a7 = LDA_F(CUR, 7, 0);                              \
    b0 = LDB_F(CUR, 0, 0); b1 = LDB_F(CUR, 1, 0);                              \
    if (pre_) STAGE_A(NXT, k1_);                                               \
    GBAR(); WLGKM0();                                                          \
    __builtin_amdgcn_s_setprio(1);                                             \
    MFMA_COL2(0, 1, b0, b1);                                                   \
    __builtin_amdgcn_s_setprio(0);                                             \
    GBAR();                                                                    \
    /* ---- sub1: B n2..3 s0 ; stage B(t+1) ---- */                            \
    b2 = LDB_F(CUR, 2, 0); b3 = LDB_F(CUR, 3, 0);                              \
    if (pre_) STAGE_B(NXT, k1_);                                               \
    GBAR(); WLGKM0();                                                          \
    __builtin_amdgcn_s_setprio(1);                                             \
    MFMA_COL2(2, 3, b2, b3);                                                   \
    __builtin_amdgcn_s_setprio(0);                                             \
    GBAR();                                                                    \
    /* ---- sub2: A frags s1 + B n0..1 s1 ---- */                              \
    a0 = LDA_F(CUR, 0, 1); a1 = LDA_F(CUR, 1, 1);                              \
    a2 = LDA_F(CUR, 2, 1); a3 = LDA_F(CUR, 3, 1);                              \
    a4 = LDA_F(CUR, 4, 1); a5 = LDA_F(CUR, 5, 1);                              \
    a6 = LDA_F(CUR, 6, 1); a7 = LDA_F(CUR, 7, 1);                              \
    b0 = LDB_F(CUR, 0, 1); b1 = LDB_F(CUR, 1, 1);                              \
    GBAR(); WLGKM0();                                                          \
    __builtin_amdgcn_s_setprio(1);                                             \
    MFMA_COL2(0, 1, b0, b1);                                                   \
    __builtin_amdgcn_s_setprio(0);                                             \
    GBAR();                                                                    \
    /* ---- sub3: B n2..3 s1 ; drain stages (3 phases of flight) ---- */       \
    b2 = LDB_F(CUR, 2, 1); b3 = LDB_F(CUR, 3, 1);                              \
    GBAR(); WLGKM0();                                                          \
    __builtin_amdgcn_s_setprio(1);                                             \
    MFMA_COL2(2, 3, b2, b3);                                                   \
    __builtin_amdgcn_s_setprio(0);                                             \
    WVM0();                                                                    \
    GBAR();                                                                    \
} while (0)

#pragma unroll 1
    for (int tk = 0; tk < NT; tk += 2) {
        TILE_STEP(0, 1, tk);
        TILE_STEP(1, 0, tk + 1);
    }

    // epilogue: C/D layout col = lane&15, row = quad*4 + reg  [m89/m91]
#pragma unroll
    for (int m = 0; m < 8; ++m) {
        const int rbase = m0 + wm * 128 + m * 16 + q * 4;
#pragma unroll
        for (int n = 0; n < 4; ++n) {
            const int col = n0 + wn * 64 + n * 16 + lo;
#pragma unroll
            for (int rr = 0; rr < 4; ++rr) {
                float v   = acc[m][n][rr];
                int   row = rbase + rr;
                if (col < DINNER) {
                    outxi[(size_t)row * DINNER + col] = (bf16_t)v;     // xi bf16
                } else {
                    float sg = 1.f / (1.f + __expf(-v));               // sigmoid(gate)
                    outg[(size_t)row * DINNER + (col - DINNER)] = (bf16_t)sg;
                }
            }
        }
    }
}

// ---------------------------------------------------------------------------
// GEMM2 gemm2_db (128x128 tile, BK=64, 4 waves, double-buffered 2-phase
// pipeline, 2 blocks/CU): out = (4096 * rowscale[row]) * ( g @ W_out^T ).
// R10: -12..18us vs the single-buffered gemm_bt2.
// ---------------------------------------------------------------------------
#define MFMA_G16()                                                  \
    MM(0, 0, a0, b0); MM(0, 1, a0, b1); MM(1, 0, a1, b0); MM(1, 1, a1, b1); \
    MM(2, 0, a2, b0); MM(2, 1, a2, b1); MM(3, 0, a3, b0); MM(3, 1, a3, b1); \
    MM(0, 2, a0, b2); MM(0, 3, a0, b3); MM(1, 2, a1, b2); MM(1, 3, a1, b3); \
    MM(2, 2, a2, b2); MM(2, 3, a2, b3); MM(3, 2, a3, b2); MM(3, 3, a3, b3)

__global__ __launch_bounds__(256)
void gemm2_db(const bf16_t* __restrict__ A, const bf16_t* __restrict__ B,
              float* __restrict__ outf, const float* __restrict__ rowscale)
{
    constexpr int K  = DINNER;   // 4096
    constexpr int NT = K / 64;   // 64 K-tiles

    __shared__ bf16_t As2[2][128 * 64];   // 16 KiB per buffer
    __shared__ bf16_t Bs2[2][128 * 64];   // 64 KiB total -> 2 blocks/CU

    const int t    = threadIdx.x;
    const int w    = t >> 6;
    const int lane = t & 63;
    const int wr   = (w >> 1) * 64;
    const int wc   = (w & 1) * 64;
    const int lo   = lane & 15;
    const int q    = lane >> 4;
    const int swz  = lo & 7;

    const int m0 = blockIdx.y * 128;
    const int n0 = blockIdx.x * 128;

    const int r_l   = lane >> 3;
    const int cb    = (lane & 7) ^ r_l;
    const int laneg = r_l * K + cb * 8;

    const bf16_t* Abase = A + (size_t)(m0 + w * 32) * K;
    const bf16_t* Bbase = B + (size_t)(n0 + w * 32) * K;

#define ST2A(BUF, kk) do {                                                     \
    _Pragma("unroll")                                                          \
    for (int c = 0; c < 4; ++c)                                                \
        __builtin_amdgcn_global_load_lds(                                      \
            (gas_ptr)(Abase + (kk) + c * 8 * K + laneg),                       \
            (las_ptr)&As2[BUF][(w * 32 + c * 8) * 64], 16, 0, 0);              \
} while (0)
#define ST2B(BUF, kk) do {                                                     \
    _Pragma("unroll")                                                          \
    for (int c = 0; c < 4; ++c)                                                \
        __builtin_amdgcn_global_load_lds(                                      \
            (gas_ptr)(Bbase + (kk) + c * 8 * K + laneg),                       \
            (las_ptr)&Bs2[BUF][(w * 32 + c * 8) * 64], 16, 0, 0);              \
} while (0)

#define LD2A(BUF, m, s) \
    (*(const bf16x8*)&As2[BUF][(wr + (m) * 16 + lo) * 64 + ((((s) * 4 + q) ^ swz) * 8)])
#define LD2B(BUF, n, s) \
    (*(const bf16x8*)&Bs2[BUF][(wc + (n) * 16 + lo) * 64 + ((((s) * 4 + q) ^ swz) * 8)])

    f32x4 acc[4][4];
#pragma unroll
    for (int i = 0; i < 4; ++i)
#pragma unroll
        for (int j = 0; j < 4; ++j) acc[i][j] = (f32x4){0.f, 0.f, 0.f, 0.f};

    // prologue
    ST2A(0, 0);
    ST2B(0, 0);
    WVM0();
    GBAR();

#define G2STEP(CUR, NXT, tkv) do {                                             \
    const int  k1_  = ((tkv) + 1) * 64;                                        \
    const bool pre_ = ((tkv) + 1) < NT;                                        \
    bf16x8 a0, a1, a2, a3, b0, b1, b2, b3;                                     \
    /* ---- phase0: all frags kk-slice 0 ; stage A+B(t+1) -> NXT ---- */       \
    a0 = LD2A(CUR, 0, 0); a1 = LD2A(CUR, 1, 0);                                \
    a2 = LD2A(CUR, 2, 0); a3 = LD2A(CUR, 3, 0);                                \
    b0 = LD2B(CUR, 0, 0); b1 = LD2B(CUR, 1, 0);                                \
    b2 = LD2B(CUR, 2, 0); b3 = LD2B(CUR, 3, 0);                                \
    if (pre_) { ST2A(NXT, k1_); ST2B(NXT, k1_); }                              \
    GBAR(); WLGKM0();                                                          \
    __builtin_amdgcn_s_setprio(1);                                             \
    MFMA_G16();                                                                \
    __builtin_amdgcn_s_setprio(0);                                             \
    GBAR();                                                                    \
    /* ---- phase1: all frags kk-slice 1 ; drain stages ---- */                \
    a0 = LD2A(CUR, 0, 1); a1 = LD2A(CUR, 1, 1);                                \
    a2 = LD2A(CUR, 2, 1); a3 = LD2A(CUR, 3, 1);                                \
    b0 = LD2B(CUR, 0, 1); b1 = LD2B(CUR, 1, 1);                                \
    b2 = LD2B(CUR, 2, 1); b3 = LD2B(CUR, 3, 1);                                \
    GBAR(); WLGKM0();                                                          \
    __builtin_amdgcn_s_setprio(1);                                             \
    MFMA_G16();                                                                \
    __builtin_amdgcn_s_setprio(0);                                             \
    WVM0();                                                                    \
    GBAR();                                                                    \
} while (0)

#pragma unroll 1
    for (int tk = 0; tk < NT; tk += 2) {
        G2STEP(0, 1, tk);
        G2STEP(1, 0, tk + 1);
    }

    // epilogue: out = acc * (4096 * rowscale[row])
#pragma unroll
    for (int mi = 0; mi < 4; ++mi) {
#pragma unroll
        for (int ni = 0; ni < 4; ++ni) {
            const int col   = n0 + wc + ni * 16 + lo;
            const int rbase = m0 + wr + mi * 16 + q * 4;
#pragma unroll
            for (int rr = 0; rr < 4; ++rr) {
                int row = rbase + rr;
                outf[(size_t)row * DMODEL + col] =
                    acc[mi][ni][rr] * (4096.0f * rowscale[row]);
            }
        }
    }
}

// ---------------------------------------------------------------------------
// conv_silu: depthwise causal conv(4) + SiLU -> xs (bf16) + u extraction
// (fp32). xi now bf16 (R11): halves the streamed read. RROWS 8: halo
// amplification 1.75 -> 1.375. No per-row accumulator state (R8 lesson).
// ---------------------------------------------------------------------------
#define RROWS 8
__global__ __launch_bounds__(256)
void conv_silu_kernel(const bf16_t* __restrict__ xi, const float* __restrict__ cw,
                      const float* __restrict__ cbias,
                      bf16_t* __restrict__ xs, float* __restrict__ uT)
{
    const int r0 = blockIdx.x * RROWS;          // 8 rows, same batch (SEQ%8==0)
    const int t  = threadIdx.x;
    const int s0 = r0 & (SEQ - 1);
    const int b  = r0 >> 11;

#pragma unroll
    for (int j = 0; j < 4; ++j) {
        const int c = t * 4 + j * 1024;
        float4 w0 = *(const float4*)(cw + (c + 0) * 4);
        float4 w1 = *(const float4*)(cw + (c + 1) * 4);
        float4 w2 = *(const float4*)(cw + (c + 2) * 4);
        float4 w3 = *(const float4*)(cw + (c + 3) * 4);
        float4 cbv = *(const float4*)(cbias + c);
        float4 xr[RROWS + 3];
#pragma unroll
        for (int i = 0; i < RROWS + 3; ++i) {
            int ss = s0 - 3 + i;
            if (ss >= 0) {
                bf16x4 v = *(const bf16x4*)(xi + (size_t)(r0 - 3 + i) * DINNER + c);
                xr[i] = make_float4((float)v[0], (float)v[1], (float)v[2], (float)v[3]);
            } else {
                xr[i] = make_float4(0.f, 0.f, 0.f, 0.f);
            }
        }
#pragma unroll
        for (int rr = 0; rr < RROWS; ++rr) {
            float4 a = xr[rr], bv = xr[rr + 1], cc = xr[rr + 2], d = xr[rr + 3];
            float v0 = cbv.x + w0.x * a.x + w0.y * bv.x + w0.z * cc.x + w0.w * d.x;
            float v1 = cbv.y + w1.x * a.y + w1.y * bv.y + w1.z * cc.y + w1.w * d.y;
            float v2 = cbv.z + w2.x * a.z + w2.y * bv.z + w2.z * cc.z + w2.w * d.z;
            float v3 = cbv.w + w3.x * a.w + w3.y * bv.w + w3.z * cc.w + w3.w * d.w;
            float o0 = v0 / (1.f + __expf(-v0));
            float o1 = v1 / (1.f + __expf(-v1));
            float o2 = v2 / (1.f + __expf(-v2));
            float o3 = v3 / (1.f + __expf(-v3));
            bf16x4 ov;
            ov[0] = (bf16_t)o0; ov[1] = (bf16_t)o1;
            ov[2] = (bf16_t)o2; ov[3] = (bf16_t)o3;
            *(bf16x4*)(xs + (size_t)(r0 + rr) * DINNER + c) = ov;
            if (j == 0 && t < 4) {                       // channels 0..15: u fp32
                uT[b * (DSTATE * SEQ) + (c + 0) * SEQ + (s0 + rr)] = o0;
                uT[b * (DSTATE * SEQ) + (c + 1) * SEQ + (s0 + rr)] = o1;
                uT[b * (DSTATE * SEQ) + (c + 2) * SEQ + (s0 + rr)] = o2;
                uT[b * (DSTATE * SEQ) + (c + 3) * SEQ + (s0 + rr)] = o3;
            }
        }
    }
}

// ---------------------------------------------------------------------------
// dt_mfma: dt = softplus(xs @ W_dt[:16]^T + b_dt) as a skinny MFMA GEMM
// (M=4096, N=16, K=4096). Block = 16 rows x 16 e; 4 waves split-K; fragments
// direct from global (L2-hot). Grid 256 = 1/CU.
// ---------------------------------------------------------------------------
__global__ __launch_bounds__(256)
void dt_mfma_kernel(const bf16_t* __restrict__ xs, const bf16_t* __restrict__ wdtb,
                    const float* __restrict__ bdt, float* __restrict__ dtT)
{
    __shared__ float red[4][256];
    const int t    = threadIdx.x;
    const int w    = t >> 6;
    const int lane = t & 63;
    const int lo   = lane & 15;
    const int q    = lane >> 4;
    const int r0   = blockIdx.x * 16;

    const bf16_t* arow = xs   + (size_t)(r0 + lo) * DINNER + w * 1024 + q * 8;
    const bf16_t* brow = wdtb + (size_t)lo        * DINNER + w * 1024 + q * 8;

    f32x4 acc = (f32x4){0.f, 0.f, 0.f, 0.f};
#pragma unroll
    for (int kt = 0; kt < 32; ++kt) {
        bf16x8 a  = *(const bf16x8*)(arow + kt * 32);
        bf16x8 bv = *(const bf16x8*)(brow + kt * 32);
        acc = __builtin_amdgcn_mfma_f32_16x16x32_bf16(a, bv, acc, 0, 0, 0);
    }
#pragma unroll
    for (int i = 0; i < 4; ++i) red[w][lane * 4 + i] = acc[i];
    __syncthreads();

    {   // t == lane*4 + i
        const int ln  = t >> 2;                  // source lane 0..63
        const int i   = t & 3;                   // reg 0..3
        const int e   = ln & 15;
        const int row = r0 + (ln >> 4) * 4 + i;
        float v = red[0][t] + red[1][t] + red[2][t] + red[3][t] + bdt[e];
        float dtv = (v > 20.f) ? v : log1pf(__expf(v));
        dtT[(row >> 11) * (DSTATE * SEQ) + e * SEQ + (row & (SEQ - 1))] = dtv;
    }
}

// ---------------------------------------------------------------------------
// segmented parallel scan: 2 blocks (one per batch) x 512 threads
//   = 16 states x 32 segments of 64 steps.  Sequential depth 160 vs 2048.
// ---------------------------------------------------------------------------
__global__ __launch_bounds__(512)
void scan2_kernel(const float* __restrict__ dtT, const float* __restrict__ uT,
                  const float* __restrict__ A_log, float* __restrict__ result)
{
    __shared__ float cont[SEQ * 17];            // 139264 B
    __shared__ float segP[DSTATE][32];
    __shared__ float segH[DSTATE][32];
    __shared__ float hin[DSTATE][32];

    const int b   = blockIdx.x;
    const int t   = threadIdx.x;
    const int n   = t >> 5;                     // 0..15
    const int seg = t & 31;                     // 0..31
    const float An = -expf(A_log[n]);

    const float* dtp = dtT + b * (DSTATE * SEQ) + n * SEQ + seg * 64;
    const float* up  = uT  + b * (DSTATE * SEQ) + n * SEQ + seg * 64;

    // pass 1: (P, H) for this segment assuming h_in = 0
    float P = 1.f, H = 0.f;
    for (int i = 0; i < 64; i += 4) {
        float4 dv = *(const float4*)(dtp + i);
        float4 uv = *(const float4*)(up + i);
        float a;
        a = 1.f + dv.x; P *= a; H = H * a + uv.x;
        a = 1.f + dv.y; P *= a; H = H * a + uv.y;
        a = 1.f + dv.z; P *= a; H = H * a + uv.z;
        a = 1.f + dv.w; P *= a; H = H * a + uv.w;
    }
    segP[n][seg] = P;
    segH[n][seg] = H;
    __syncthreads();

    // exclusive affine prefix over 32 segments, serial per state
    if (t < DSTATE) {
        float h = 0.f;
#pragma unroll
        for (int j = 0; j < 32; ++j) {
            hin[t][j] = h;
            h = segP[t][j] * h + segH[t][j];
        }
    }
    __syncthreads();

    // pass 2: replay with correct h_in; write h*An (n-swizzled)
    {
        float h = hin[n][seg];
        const int nsw = (n + seg) & 15;
        for (int i = 0; i < 64; i += 4) {
            float4 dv = *(const float4*)(dtp + i);
            float4 uv = *(const float4*)(up + i);
            const int s = seg * 64 + i;
            h = h * (1.f + dv.x) + uv.x; cont[(s + 0) * 17 + nsw] = h * An;
            h = h * (1.f + dv.y) + uv.y; cont[(s + 1) * 17 + nsw] = h * An;
            h = h * (1.f + dv.z) + uv.z; cont[(s + 2) * 17 + nsw] = h * An;
            h = h * (1.f + dv.w) + uv.w; cont[(s + 3) * 17 + nsw] = h * An;
        }
    }
    __syncthreads();

    // reduce over the 16 states; lane stride 17 words -> conflict-free
#pragma unroll
    for (int k = 0; k < 4; ++k) {
        const int s = t + k * 512;
        float sum = 0.f;
#pragma unroll
        for (int j = 0; j < DSTATE; ++j) sum += cont[s * 17 + j];
        result[b * SEQ + s] = sum;
    }
}

// ---------------------------------------------------------------------------
// launch
// ---------------------------------------------------------------------------
extern "C" void kernel_launch(void* const* d_in, const int* in_sizes, int n_in,
                              void* d_out, int out_size, void* d_ws, size_t ws_size,
                              hipStream_t stream)
{
    const float* x      = (const float*)d_in[0];
    const float* W_in   = (const float*)d_in[1];
    const float* conv_w = (const float*)d_in[2];
    const float* conv_b = (const float*)d_in[3];
    const float* W_dt   = (const float*)d_in[4];
    const float* b_dt   = (const float*)d_in[5];
    const float* A_log  = (const float*)d_in[6];
    const float* W_out  = (const float*)d_in[7];
    float* out = (float*)d_out;

    const size_t MB = 1u << 20;
    char* w = (char*)d_ws;
    bf16_t* xb   = (bf16_t*)(w);                     // 16 MB
    bf16_t* wib  = (bf16_t*)(w + 16 * MB);           // 32 MB
    bf16_t* wob  = (bf16_t*)(w + 48 * MB);           // 16 MB
    bf16_t* xi   = (bf16_t*)(w + 64 * MB);           // 32 MB (bf16, R11)
    bf16_t* g    = (bf16_t*)(w + 128 * MB);          // 32 MB
    float*  uT   = (float*) (w + 160 * MB);                      // 256 KB
    float*  dtT  = (float*) (w + 160 * MB + 262144);             // 256 KB
    float*  res  = (float*) (w + 160 * MB + 2 * 262144);         // 16 KB
    bf16_t* xs   = (bf16_t*)(w + 161 * MB);          // 32 MB
    bf16_t* wdtb = (bf16_t*)(w + 193 * MB);          // 128 KB

    // 1. merged casts to bf16 (W_in, x, W_out, W_dt[:16])
    cast_all_kernel<<<CAST_BLOCKS, 256, 0, stream>>>(W_in, wib, x, xb, W_out, wob,
                                                     W_dt, wdtb);

    // 2. GEMM1 (256^2, R1 schedule): x @ W_in^T -> xi bf16 | g bf16
    gemm1_256<<<dim3(32, 16), 512, 0, stream>>>(xb, wib, xi, g);

    // 3a. conv + silu -> xs bf16, u fp32
    conv_silu_kernel<<<NROWS / RROWS, 256, 0, stream>>>(xi, conv_w, conv_b, xs, uT);

    // 3b. dt = softplus(xs @ W_dt[:16]^T + b) via MFMA
    dt_mfma_kernel<<<NROWS / 16, 256, 0, stream>>>(xs, wdtb, b_dt, dtT);

    // 4. segmented parallel scan -> res[b*S+s]
    scan2_kernel<<<2, 512, 0, stream>>>(dtT, uT, A_log, res);

    // 5. GEMM2 (gemm2_db: dbuf-pipelined 128^2, 2 blocks/CU)
    gemm2_db<<<dim3(16, 32), 256, 0, stream>>>(g, wob, out, res);
}